// Round 9
// baseline (2163.402 us; speedup 1.0000x reference)
//
#include <hip/hip_runtime.h>
#include <hip/hip_bf16.h>
#include <math.h>

// Problem constants
#define HID       300
#define HP        320
#define NH        4
#define E_BONDS   60000
#define NATOMS    30000
#define KNB       6
#define NMOLS     600
#define APM       50
#define AFD       144
#define BONDIN    158

typedef unsigned short u16;
typedef unsigned int   u32;
typedef _Float16 f16;
typedef f16   f16x8 __attribute__((ext_vector_type(8)));
typedef float f32x4 __attribute__((ext_vector_type(4)));

// ---------------- helpers ----------------
__device__ inline float hlo(u32 u) { union { u32 i; f16 h[2]; } c; c.i = u; return (float)c.h[0]; }
__device__ inline float hhi(u32 u) { union { u32 i; f16 h[2]; } c; c.i = u; return (float)c.h[1]; }
__device__ inline u32 packh2(float a, float b) {
    union { u32 i; f16 h[2]; } c; c.h[0] = (f16)a; c.h[1] = (f16)b; return c.i;
}

__device__ inline void gl2lds16(const void* g, void* l) {
    __builtin_amdgcn_global_load_lds(
        (const __attribute__((address_space(1))) void*)g,
        (__attribute__((address_space(3))) void*)l, 16, 0, 0);
}

// ---------------------------------------------------------------------------
// MFMA GEMM (proven round 4): C = A[M][lda] @ B[Nb][ldb]^T, f16 in.
// EPI: 0 Cf=v | 1 Ch=h(v) | 2 Ch=h(v),out2=h(relu v) | 3 v+=resid,relu,Ch
//      4 v+=Cf+bias,relu,Cf&Ch | 5 v+=bias,relu,Cf
// ---------------------------------------------------------------------------
template <int BN, int EPI>
__global__ __launch_bounds__(256) void mfma_gemm_k(
    const f16* __restrict__ A, int lda,
    const f16* __restrict__ B, int ldb,
    int M, int Nb, int K, int ldc,
    float* __restrict__ Cf, f16* __restrict__ Ch,
    const float* __restrict__ bias,
    const f16* __restrict__ resid,
    f16* __restrict__ out2)
{
    constexpr int NF = BN / 32;
    __shared__ f16 sA[128 * 64];
    __shared__ f16 sB[BN * 64];
    const int tid  = threadIdx.x;
    const int lane = tid & 63;
    const int wv   = tid >> 6;
    const int wm   = wv >> 1, wn = wv & 1;
    const int m0   = blockIdx.x * 128, n0 = blockIdx.y * BN;

    f32x4 acc[4][NF];
#pragma unroll
    for (int i = 0; i < 4; ++i)
#pragma unroll
        for (int j = 0; j < NF; ++j) acc[i][j] = (f32x4){0.f, 0.f, 0.f, 0.f};

    for (int k0 = 0; k0 < K; k0 += 64) {
        __syncthreads();
#pragma unroll
        for (int i = 0; i < 4; ++i) {
            int o   = (((i * 4 + wv) * 64) + lane) * 16;
            int row = o >> 7;
            int p   = (o >> 4) & 7;
            int gr  = m0 + row; gr = gr < M ? gr : M - 1;
            const f16* g = A + (size_t)gr * lda + k0 + ((p ^ (row & 7)) << 3);
            gl2lds16(g, (char*)sA + (i * 4 + wv) * 1024);
        }
#pragma unroll
        for (int i = 0; i < BN / 32; ++i) {
            int o   = (((i * 4 + wv) * 64) + lane) * 16;
            int row = o >> 7;
            int p   = (o >> 4) & 7;
            int gr  = n0 + row; gr = gr < Nb ? gr : Nb - 1;
            const f16* g = B + (size_t)gr * ldb + k0 + ((p ^ (row & 7)) << 3);
            gl2lds16(g, (char*)sB + (i * 4 + wv) * 1024);
        }
        __syncthreads();

        const int rl = lane & 15, cl = lane >> 4;
#pragma unroll
        for (int kh = 0; kh < 2; ++kh) {
            f16x8 af[4], bfr[NF];
#pragma unroll
            for (int mf = 0; mf < 4; ++mf) {
                int row = wm * 64 + mf * 16 + rl;
                int ch  = (kh * 4 + cl) ^ (row & 7);
                af[mf]  = *(const f16x8*)&sA[row * 64 + ch * 8];
            }
#pragma unroll
            for (int nf = 0; nf < NF; ++nf) {
                int row = wn * (BN / 2) + nf * 16 + rl;
                int ch  = (kh * 4 + cl) ^ (row & 7);
                bfr[nf] = *(const f16x8*)&sB[row * 64 + ch * 8];
            }
#pragma unroll
            for (int mf = 0; mf < 4; ++mf)
#pragma unroll
                for (int nf = 0; nf < NF; ++nf)
                    acc[mf][nf] = __builtin_amdgcn_mfma_f32_16x16x32_f16(
                        af[mf], bfr[nf], acc[mf][nf], 0, 0, 0);
        }
    }

    const int rl = lane & 15, cl = lane >> 4;
#pragma unroll
    for (int mf = 0; mf < 4; ++mf) {
#pragma unroll
        for (int r = 0; r < 4; ++r) {
            int gm = m0 + wm * 64 + mf * 16 + cl * 4 + r;
            if (gm >= M) continue;
#pragma unroll
            for (int nf = 0; nf < NF; ++nf) {
                int gn = n0 + wn * (BN / 2) + nf * 16 + rl;
                if (gn >= ldc) continue;
                float v = acc[mf][nf][r];
                size_t ci = (size_t)gm * ldc + gn;
                if (EPI == 0) {
                    Cf[ci] = v;
                } else if (EPI == 1) {
                    Ch[ci] = (f16)v;
                } else if (EPI == 2) {
                    Ch[ci] = (f16)v;
                    out2[ci] = (f16)fmaxf(v, 0.f);
                } else if (EPI == 3) {
                    v += (float)resid[ci];
                    Ch[ci] = (f16)fmaxf(v, 0.f);
                } else if (EPI == 4) {
                    v += Cf[ci];
                    v += (gn < HID) ? bias[gn] : 0.f;
                    v = fmaxf(v, 0.f);
                    Cf[ci] = v; Ch[ci] = (f16)v;
                } else {
                    v += (gn < HID) ? bias[gn] : 0.f;
                    Cf[ci] = fmaxf(v, 0.f);
                }
            }
        }
    }
}

// ---------------------------------------------------------------------------
// FUSED message-passing iteration (v5 — nei hoisted across all heads).
// nei[2][6][10] = 120 VGPRs gathered ONCE at block start (bgraph is random,
// so gathers are L3-served; 4x cross-head redundancy eliminated: 922->230 MB
// per dispatch). 512 thr / 8 waves / 2 per SIMD => 256-reg budget; peak live
// ~225. Per head: GEMM1 -> sMC, score/softmax/comp (2 unrolled bond-half
// passes, 16 thr/bond), GEMM2 accumulate. Epilogue relu(binput + acc2).
// ---------------------------------------------------------------------------
#define SMC_LD 328   // 320 + 8 pad

__global__ __launch_bounds__(512, 2) void fused_mp_k(
    const f16* __restrict__ msgIn,   // [E][320]
    f16* __restrict__ msgOut,        // [E][320]
    const f16* __restrict__ binh,    // [E][320]
    const int* __restrict__ bgraph,  // [E][6]
    const f16* __restrict__ WmaT,    // [4*320][320]  row n*320+d, col h
    const f16* __restrict__ WhT2)    // [4*320][320]  row n*320+h, col d
{
    __shared__ f16 sMsg[64 * 320];        // 40 KB, XOR-swizzled 16B chunks
    __shared__ f16 sMC[64 * SMC_LD];      // 41 KB, mt/comp (padded rows)
    __shared__ f16 sB[320 * 64];          // 40 KB, weight k-chunk (swizzled)

    const int tid  = threadIdx.x;
    const int lane = tid & 63;
    const int wv   = tid >> 6;            // 0..7
    const int wm   = wv >> 2;             // 0..1
    const int wn   = wv & 3;              // 0..3
    const int rl   = lane & 15, cl = lane >> 4;
    const int e0   = blockIdx.x * 64;
    const int tq   = tid & 15;            // 16-thr group lane (score phase)

    // ---- gather nei for BOTH bond-half passes, ONCE, held across heads ----
    u32 nei[2][KNB][10];
#pragma unroll
    for (int p = 0; p < 2; ++p) {
        int gb = p * 32 + (tid >> 4);
        int eg = e0 + gb; eg = eg < E_BONDS ? eg : E_BONDS - 1;
#pragma unroll
        for (int k = 0; k < KNB; ++k) {
            int nb = bgraph[eg * KNB + k];
            const u32* q = (const u32*)msgIn + (size_t)nb * (HP / 2) + tq * 10;
#pragma unroll
            for (int j = 0; j < 10; ++j) nei[p][k][j] = q[j];
        }
    }

    // ---- stage sMsg: 2560 16B-chunks (40 per row), wave-uniform dests ----
    for (int wc = wv; wc < 40; wc += 8) {
        int q   = wc * 64 + lane;
        int row = q / 40, c = q - row * 40;
        int gr  = e0 + row; gr = gr < E_BONDS ? gr : E_BONDS - 1;
        gl2lds16(msgIn + (size_t)gr * HP + ((c ^ (row & 7)) << 3),
                 (char*)sMsg + wc * 1024);
    }
    __syncthreads();

    f32x4 acc2[2][5];
#pragma unroll
    for (int mf = 0; mf < 2; ++mf)
#pragma unroll
        for (int nf = 0; nf < 5; ++nf) acc2[mf][nf] = (f32x4){0.f, 0.f, 0.f, 0.f};

#pragma unroll 1
    for (int n = 0; n < NH; ++n) {
        // ================= GEMM1: mt_n = sMsg @ WmaT_n =================
        const f16* B1 = WmaT + (size_t)n * HP * HP;
        f32x4 acc1[2][5];
#pragma unroll
        for (int mf = 0; mf < 2; ++mf)
#pragma unroll
            for (int nf = 0; nf < 5; ++nf) acc1[mf][nf] = (f32x4){0.f, 0.f, 0.f, 0.f};

        for (int kc = 0; kc < 5; ++kc) {
            __syncthreads();
            for (int wc = wv; wc < 40; wc += 8) {
                int q = wc * 64 + lane;
                int brow = q >> 3, c = q & 7;
                gl2lds16(B1 + (size_t)brow * HP + kc * 64 + ((c ^ (brow & 7)) << 3),
                         (char*)sB + wc * 1024);
            }
            __syncthreads();
#pragma unroll
            for (int lk = 0; lk < 2; ++lk) {
                f16x8 a[2];
#pragma unroll
                for (int mf = 0; mf < 2; ++mf) {
                    int arow = wm * 32 + mf * 16 + rl;
                    int ach  = (kc * 8 + lk * 4 + cl) ^ (rl & 7);
                    a[mf] = *(const f16x8*)&sMsg[arow * HP + ach * 8];
                }
#pragma unroll
                for (int nf = 0; nf < 5; ++nf) {
                    int brow = (wn + nf * 4) * 16 + rl;
                    int bch  = (lk * 4 + cl) ^ (rl & 7);
                    f16x8 b  = *(const f16x8*)&sB[brow * 64 + bch * 8];
                    acc1[0][nf] = __builtin_amdgcn_mfma_f32_16x16x32_f16(a[0], b, acc1[0][nf], 0, 0, 0);
                    acc1[1][nf] = __builtin_amdgcn_mfma_f32_16x16x32_f16(a[1], b, acc1[1][nf], 0, 0, 0);
                }
            }
        }
        // scatter mt to sMC
#pragma unroll
        for (int mf = 0; mf < 2; ++mf)
#pragma unroll
            for (int nf = 0; nf < 5; ++nf) {
#pragma unroll
                for (int r = 0; r < 4; ++r) {
                    int row = wm * 32 + mf * 16 + cl * 4 + r;
                    int col = (wn + nf * 4) * 16 + rl;
                    sMC[row * SMC_LD + col] = (f16)acc1[mf][nf][r];
                }
            }
        __syncthreads();

        // ===== score/softmax/comp: 16 thr/bond, 2 unrolled passes =====
#pragma unroll
        for (int p = 0; p < 2; ++p) {
            const int gb = p * 32 + (tid >> 4);

            // ---- scores ----
            float pk[KNB] = {0.f, 0.f, 0.f, 0.f, 0.f, 0.f};
            const u32* mp = (const u32*)&sMC[gb * SMC_LD] + tq * 10;
#pragma unroll
            for (int j = 0; j < 10; ++j) {
                u32 mtv = mp[j];
                float m0 = hlo(mtv), m1 = hhi(mtv);
#pragma unroll
                for (int k = 0; k < KNB; ++k)
                    pk[k] += hlo(nei[p][k][j]) * m0 + hhi(nei[p][k][j]) * m1;
            }
#pragma unroll
            for (int s = 1; s < 16; s <<= 1)
#pragma unroll
                for (int k = 0; k < KNB; ++k) pk[k] += __shfl_xor(pk[k], s);

            float mx = pk[0];
#pragma unroll
            for (int k = 1; k < KNB; ++k) mx = fmaxf(mx, pk[k]);
            float w[KNB], sum = 0.f;
#pragma unroll
            for (int k = 0; k < KNB; ++k) { w[k] = __expf(pk[k] - mx); sum += w[k]; }
            float inv = 1.f / sum;
#pragma unroll
            for (int k = 0; k < KNB; ++k) w[k] *= inv;

            // ---- comp (in-place over mt; own cells only) ----
            u32* cp = (u32*)&sMC[gb * SMC_LD] + tq * 10;
#pragma unroll
            for (int j = 0; j < 10; ++j) {
                float c0 = 0.f, c1 = 0.f;
#pragma unroll
                for (int k = 0; k < KNB; ++k) {
                    c0 += w[k] * hlo(nei[p][k][j]);
                    c1 += w[k] * hhi(nei[p][k][j]);
                }
                cp[j] = packh2(c0, c1);
            }
        }
        __syncthreads();

        // ============ GEMM2: acc2 += comp_n @ WhT2_n ============
        const f16* B2 = WhT2 + (size_t)n * HP * HP;
        for (int kc = 0; kc < 5; ++kc) {
            __syncthreads();
            for (int wc = wv; wc < 40; wc += 8) {
                int q = wc * 64 + lane;
                int brow = q >> 3, c = q & 7;
                gl2lds16(B2 + (size_t)brow * HP + kc * 64 + ((c ^ (brow & 7)) << 3),
                         (char*)sB + wc * 1024);
            }
            __syncthreads();
#pragma unroll
            for (int lk = 0; lk < 2; ++lk) {
                f16x8 a[2];
#pragma unroll
                for (int mf = 0; mf < 2; ++mf) {
                    int arow = wm * 32 + mf * 16 + rl;
                    a[mf] = *(const f16x8*)&sMC[arow * SMC_LD + kc * 64 + lk * 32 + cl * 8];
                }
#pragma unroll
                for (int nf = 0; nf < 5; ++nf) {
                    int brow = (wn + nf * 4) * 16 + rl;
                    int bch  = (lk * 4 + cl) ^ (rl & 7);
                    f16x8 b  = *(const f16x8*)&sB[brow * 64 + bch * 8];
                    acc2[0][nf] = __builtin_amdgcn_mfma_f32_16x16x32_f16(a[0], b, acc2[0][nf], 0, 0, 0);
                    acc2[1][nf] = __builtin_amdgcn_mfma_f32_16x16x32_f16(a[1], b, acc2[1][nf], 0, 0, 0);
                }
            }
        }
        __syncthreads();   // protect sMC before next head's scatter
    }

    // ---- epilogue: msg_out = relu(binput + acc2) ----
#pragma unroll
    for (int mf = 0; mf < 2; ++mf)
#pragma unroll
        for (int nf = 0; nf < 5; ++nf) {
#pragma unroll
            for (int r = 0; r < 4; ++r) {
                int gm = e0 + wm * 32 + mf * 16 + cl * 4 + r;
                if (gm >= E_BONDS) continue;
                int col = (wn + nf * 4) * 16 + rl;
                size_t ci = (size_t)gm * HP + col;
                float v = acc2[mf][nf][r] + (float)binh[ci];
                msgOut[ci] = (f16)fmaxf(v, 0.f);
            }
        }
}

// ---------------------------------------------------------------------------
// a_nei[a] = sum_k msg[agraph[a][k]]
// ---------------------------------------------------------------------------
__global__ void gather_sum_h_k(const f16* __restrict__ msg,
                               const int* __restrict__ agraph,
                               f16* __restrict__ out) {
    int idx = blockIdx.x * 256 + threadIdx.x;
    if (idx >= NATOMS * (HP / 2)) return;
    int a = idx / (HP / 2), c = idx - a * (HP / 2);
    const int* g = agraph + (size_t)a * KNB;
    float s0 = 0.f, s1 = 0.f;
#pragma unroll
    for (int k = 0; k < KNB; ++k) {
        u32 u = *(const u32*)(msg + (size_t)g[k] * HP + c * 2);
        s0 += hlo(u); s1 += hhi(u);
    }
    ((u32*)out)[idx] = packh2(s0, s1);
}

// ---------------------------------------------------------------------------
__global__ void conv_pad_k(const float* __restrict__ src, f16* __restrict__ dst,
                           int R, int C, int CP) {
    int idx = blockIdx.x * 256 + threadIdx.x;
    if (idx >= R * CP) return;
    int r = idx / CP, c = idx - r * CP;
    dst[idx] = (f16)(c < C ? src[(size_t)r * C + c] : 0.f);
}

// ---------------------------------------------------------------------------
// Weight prep -> f16, padded, K-contiguous layouts.
// mode 0: WiT[320][192]   <- W_i[300][158]
// mode 1: WmaT[1280][320] <- row n*320+d, col h = W_ma[n][h][d]
// mode 2: WhT2[1280][320] <- row n*320+h, col d = W_h[h][n*300+d]
// mode 3: WoA[320][192]   <- W_o cols 0..143
// mode 4: WoB[320][320]   <- W_o cols 144..443
// else:   [320][320]      <- [300][300]
// ---------------------------------------------------------------------------
__global__ void prep_w_k(const float* __restrict__ src, f16* __restrict__ dst,
                         int mode, int R, int CK) {
    int idx = blockIdx.x * 256 + threadIdx.x;
    if (idx >= R * CK) return;
    int r = idx / CK, c = idx - r * CK;
    float v = 0.f;
    if (mode == 0) {
        if (r < HID && c < BONDIN) v = src[r * BONDIN + c];
    } else if (mode == 1) {
        int n = r / HP, d = r - n * HP;
        if (d < HID && c < HID) v = src[((size_t)n * HID + c) * HID + d];
    } else if (mode == 2) {
        int n = r / HP, h = r - n * HP;
        if (h < HID && c < HID) v = src[(size_t)h * (NH * HID) + n * HID + c];
    } else if (mode == 3) {
        if (r < HID && c < AFD) v = src[r * (AFD + HID) + c];
    } else if (mode == 4) {
        if (r < HID && c < HID) v = src[r * (AFD + HID) + AFD + c];
    } else {
        if (r < HID && c < HID) v = src[r * HID + c];
    }
    dst[idx] = (f16)v;
}

// ---------------------------------------------------------------------------
// MFMA molecule attention (unchanged from round 4).
// ---------------------------------------------------------------------------
__global__ __launch_bounds__(256) void mol_attn_mfma_k(
    const f16* __restrict__ atomHh,
    const f16* __restrict__ ah2h,
    f16* __restrict__ comp2h)
{
    __shared__ f16 sCur[64 * 320];
    __shared__ float sP[64][66];
    const int tid  = threadIdx.x;
    const int lane = tid & 63;
    const int wv   = tid >> 6;
    const int m    = blockIdx.x;
    const int rl   = lane & 15, cl = lane >> 4;

#pragma unroll
    for (int i = 0; i < 10; ++i) {
        int g   = i * 256 + wv * 64 + lane;
        int row = g / 40, c = g - row * 40;
        int grow = m * APM + row; grow = grow < NATOMS ? grow : NATOMS - 1;
        const f16* src = atomHh + (size_t)grow * HP + ((c ^ (row & 7)) << 3);
        gl2lds16(src, (char*)sCur + (size_t)(i * 256 + wv * 64) * 16);
    }
    __syncthreads();

    f32x4 acc[4];
#pragma unroll
    for (int nf = 0; nf < 4; ++nf) acc[nf] = (f32x4){0.f, 0.f, 0.f, 0.f};
    int qrow = m * APM + wv * 16 + rl;
    qrow = qrow < NATOMS ? qrow : NATOMS - 1;
    const f16* qbase = ah2h + (size_t)qrow * HP;
#pragma unroll
    for (int kh = 0; kh < 10; ++kh) {
        f16x8 aq = *(const f16x8*)(qbase + kh * 32 + cl * 8);
#pragma unroll
        for (int nf = 0; nf < 4; ++nf) {
            int brow = nf * 16 + rl;
            int ch   = (kh * 4 + cl) ^ (brow & 7);
            f16x8 bv = *(const f16x8*)&sCur[brow * 320 + ch * 8];
            acc[nf] = __builtin_amdgcn_mfma_f32_16x16x32_f16(aq, bv, acc[nf], 0, 0, 0);
        }
    }

#pragma unroll
    for (int r = 0; r < 4; ++r) {
        float s[4];
#pragma unroll
        for (int nf = 0; nf < 4; ++nf) {
            s[nf] = acc[nf][r];
            if (nf == 3 && rl >= 2) s[nf] = -1e30f;
        }
        float mx = fmaxf(fmaxf(s[0], s[1]), fmaxf(s[2], s[3]));
#pragma unroll
        for (int msk = 1; msk < 16; msk <<= 1) mx = fmaxf(mx, __shfl_xor(mx, msk));
        float e[4], sum = 0.f;
#pragma unroll
        for (int nf = 0; nf < 4; ++nf) { e[nf] = __expf(s[nf] - mx); sum += e[nf]; }
#pragma unroll
        for (int msk = 1; msk < 16; msk <<= 1) sum += __shfl_xor(sum, msk);
        float inv = 1.f / sum;
        int a = wv * 16 + cl * 4 + r;
#pragma unroll
        for (int nf = 0; nf < 4; ++nf) sP[a][nf * 16 + rl] = e[nf] * inv;
    }
    __syncthreads();

    const int a  = tid >> 2, hq = tid & 3;
    const bool aval = a < APM;
    const size_t orow = (size_t)(m * APM + a) * HP;
#pragma unroll
    for (int p = 0; p < 2; ++p) {
        float av[40];
#pragma unroll
        for (int i = 0; i < 40; ++i) av[i] = 0.f;
        const int ch0 = p * 20 + hq * 5;
        for (int b = 0; b < APM; ++b) {
            float w = sP[a][b];
#pragma unroll
            for (int i = 0; i < 5; ++i) {
                int ch = (ch0 + i) ^ (b & 7);
                f16x8 cv = *(const f16x8*)&sCur[b * 320 + ch * 8];
#pragma unroll
                for (int j = 0; j < 8; ++j) av[i * 8 + j] += w * (float)cv[j];
            }
        }
        if (aval) {
#pragma unroll
            for (int i = 0; i < 5; ++i) {
                f16x8 o;
#pragma unroll
                for (int j = 0; j < 8; ++j) o[j] = (f16)av[i * 8 + j];
                *(f16x8*)&comp2h[orow + p * 160 + hq * 40 + i * 8] = o;
            }
        }
    }
}

__global__ void mol_reduce_k(const float* __restrict__ atomH,
                             const float* __restrict__ atth,
                             float* __restrict__ out) {
    const int m = blockIdx.x;
    for (int h = threadIdx.x; h < HID; h += 256) {
        float s = 0.f;
        for (int a = 0; a < APM; ++a) {
            size_t i = (size_t)(m * APM + a) * HP + h;
            s += atomH[i] + atth[i];
        }
        out[(size_t)m * HID + h] = s * (1.f / APM);
    }
}

// ---------------------------------------------------------------------------
extern "C" void kernel_launch(void* const* d_in, const int* in_sizes, int n_in,
                              void* d_out, int out_size, void* d_ws, size_t ws_size,
                              hipStream_t stream) {
    const float* fatoms = (const float*)d_in[0];
    const float* fbonds = (const float*)d_in[1];
    const int*   agraph = (const int*)d_in[2];
    const int*   bgraph = (const int*)d_in[3];
    const float* W_i    = (const float*)d_in[4];
    const float* W_ma   = (const float*)d_in[5];
    const float* W_h    = (const float*)d_in[6];
    const float* W_o    = (const float*)d_in[7];
    const float* b_o    = (const float*)d_in[8];
    const float* W_a    = (const float*)d_in[9];
    const float* W_b    = (const float*)d_in[10];
    const float* b_b    = (const float*)d_in[11];
    float* out = (float*)d_out;

    // ---- workspace layout (max 213.7 MB) ----
    char* ws = (char*)d_ws;
    f16* msgA    = (f16*)(ws);                        // [60000][320]
    f16* msgB    = (f16*)(ws + 38400000);             // [60000][320]
    f16* binh    = (f16*)(ws + 76800000);             // [60000][320]
    f16* fbondsh = (f16*)(ws + 115200000);            // [60000][192] (pre-MP)
    // post-MP aliases:
    f16* aneih   = (f16*)(ws);                        // over msgA (dead)
    f16* fatomsh = (f16*)(ws + 38400000);             // over msgB (dead after gather)
    float* atomH = (float*)(ws + 76800000);           // over binh (dead)
    f16* atomHh  = (f16*)(ws + 115200000);
    f16* ah2h    = (f16*)(ws + 134400000);
    f16* comp2h  = (f16*)(ws + 153600000);
    float* atth  = (float*)(ws + 172800000);          // ends 211.2MB
    char* wb = ws + 211200000;
    f16* WiT  = (f16*)(wb);
    f16* WmaT = (f16*)(wb + 122880);
    f16* WhT2 = (f16*)(wb + 942080);
    f16* WoA  = (f16*)(wb + 1761280);
    f16* WoB  = (f16*)(wb + 1884160);
    f16* Wa   = (f16*)(wb + 2088960);
    f16* Wb   = (f16*)(wb + 2293760);

    // ---- weight/input prep ----
    prep_w_k<<<dim3((320 * 192 + 255) / 256), dim3(256), 0, stream>>>(W_i, WiT, 0, 320, 192);
    prep_w_k<<<dim3((1280 * 320 + 255) / 256), dim3(256), 0, stream>>>(W_ma, WmaT, 1, 1280, 320);
    prep_w_k<<<dim3((1280 * 320 + 255) / 256), dim3(256), 0, stream>>>(W_h, WhT2, 2, 1280, 320);
    prep_w_k<<<dim3((320 * 192 + 255) / 256), dim3(256), 0, stream>>>(W_o, WoA, 3, 320, 192);
    prep_w_k<<<dim3((320 * 320 + 255) / 256), dim3(256), 0, stream>>>(W_o, WoB, 4, 320, 320);
    prep_w_k<<<dim3((320 * 320 + 255) / 256), dim3(256), 0, stream>>>(W_a, Wa, 5, 320, 320);
    prep_w_k<<<dim3((320 * 320 + 255) / 256), dim3(256), 0, stream>>>(W_b, Wb, 6, 320, 320);
    conv_pad_k<<<dim3((E_BONDS * 192 + 255) / 256), dim3(256), 0, stream>>>(
        fbonds, fbondsh, E_BONDS, BONDIN, 192);

    // ---- binput/message0 ----
    mfma_gemm_k<128, 2><<<dim3(469, 3), dim3(256), 0, stream>>>(
        fbondsh, 192, WiT, 192, E_BONDS, 320, 192, HP, nullptr, binh, nullptr, nullptr, msgA);

    // ---- 3 fused message-passing iterations (ping-pong msgA <-> msgB) ----
    fused_mp_k<<<dim3(938), dim3(512), 0, stream>>>(msgA, msgB, binh, bgraph, WmaT, WhT2);
    fused_mp_k<<<dim3(938), dim3(512), 0, stream>>>(msgB, msgA, binh, bgraph, WmaT, WhT2);
    fused_mp_k<<<dim3(938), dim3(512), 0, stream>>>(msgA, msgB, binh, bgraph, WmaT, WhT2);

    // ---- atom stage ----
    gather_sum_h_k<<<dim3((NATOMS * 160 + 255) / 256), dim3(256), 0, stream>>>(msgB, agraph, aneih);
    conv_pad_k<<<dim3((NATOMS * 192 + 255) / 256), dim3(256), 0, stream>>>(
        fatoms, fatomsh, NATOMS, AFD, 192);
    mfma_gemm_k<128, 0><<<dim3(235, 3), dim3(256), 0, stream>>>(
        fatomsh, 192, WoA, 192, NATOMS, 320, 192, HP, atomH, nullptr, nullptr, nullptr, nullptr);
    mfma_gemm_k<128, 4><<<dim3(235, 3), dim3(256), 0, stream>>>(
        aneih, HP, WoB, HP, NATOMS, 320, HP, HP, atomH, atomHh, b_o, nullptr, nullptr);

    // ---- molecule attention ----
    mfma_gemm_k<128, 1><<<dim3(235, 3), dim3(256), 0, stream>>>(
        atomHh, HP, Wa, HP, NATOMS, 320, HP, HP, nullptr, ah2h, nullptr, nullptr, nullptr);
    mol_attn_mfma_k<<<dim3(NMOLS), dim3(256), 0, stream>>>(atomHh, ah2h, comp2h);
    mfma_gemm_k<128, 5><<<dim3(235, 3), dim3(256), 0, stream>>>(
        comp2h, HP, Wb, HP, NATOMS, 320, HP, HP, atth, nullptr, b_b, nullptr, nullptr);
    mol_reduce_k<<<dim3(NMOLS), dim3(256), 0, stream>>>(atomH, atth, out);
}

// Round 10
// 1336.321 us; speedup vs baseline: 1.6189x; 1.6189x over previous
//
#include <hip/hip_runtime.h>
#include <hip/hip_bf16.h>
#include <math.h>

// Problem constants
#define HID       300
#define HP        320
#define NH        4
#define E_BONDS   60000
#define NATOMS    30000
#define KNB       6
#define NMOLS     600
#define APM       50
#define AFD       144
#define BONDIN    158

typedef unsigned short u16;
typedef unsigned int   u32;
typedef _Float16 f16;
typedef f16   f16x8 __attribute__((ext_vector_type(8)));
typedef float f32x4 __attribute__((ext_vector_type(4)));

// ---------------- helpers ----------------
__device__ inline float hlo(u32 u) { union { u32 i; f16 h[2]; } c; c.i = u; return (float)c.h[0]; }
__device__ inline float hhi(u32 u) { union { u32 i; f16 h[2]; } c; c.i = u; return (float)c.h[1]; }
__device__ inline u32 packh2(float a, float b) {
    union { u32 i; f16 h[2]; } c; c.h[0] = (f16)a; c.h[1] = (f16)b; return c.i;
}

__device__ inline void gl2lds16(const void* g, void* l) {
    __builtin_amdgcn_global_load_lds(
        (const __attribute__((address_space(1))) void*)g,
        (__attribute__((address_space(3))) void*)l, 16, 0, 0);
}

// ---------------------------------------------------------------------------
// MFMA GEMM: C = A[M][lda]_f16 @ B[Nb][ldb]_f16^T   (B pre-transposed: [N][K])
// Tile 128xBN, BK=64, 256 thr = 4 waves (2x2), wave = 64 x BN/2.
// BN=160 -> grid.y=2 covers N=320 exactly; BN=256 -> grid.y=5 covers 1280.
// EPI: 0 Cf=v | 1 Ch=h(v) | 2 Ch=h(v),out2=h(relu v) | 3 v+=resid,relu,Ch
//      4 v+=Cf+bias,relu,Cf&Ch | 5 v+=bias,relu,Cf
// ---------------------------------------------------------------------------
template <int BN, int EPI>
__global__ __launch_bounds__(256) void mfma_gemm_k(
    const f16* __restrict__ A, int lda,
    const f16* __restrict__ B, int ldb,
    int M, int Nb, int K, int ldc,
    float* __restrict__ Cf, f16* __restrict__ Ch,
    const float* __restrict__ bias,
    const f16* __restrict__ resid,
    f16* __restrict__ out2)
{
    constexpr int NF = BN / 32;
    __shared__ f16 sA[128 * 64];
    __shared__ f16 sB[BN * 64];
    const int tid  = threadIdx.x;
    const int lane = tid & 63;
    const int wv   = tid >> 6;
    const int wm   = wv >> 1, wn = wv & 1;
    const int m0   = blockIdx.x * 128, n0 = blockIdx.y * BN;

    f32x4 acc[4][NF];
#pragma unroll
    for (int i = 0; i < 4; ++i)
#pragma unroll
        for (int j = 0; j < NF; ++j) acc[i][j] = (f32x4){0.f, 0.f, 0.f, 0.f};

    for (int k0 = 0; k0 < K; k0 += 64) {
        __syncthreads();
#pragma unroll
        for (int i = 0; i < 4; ++i) {
            int o   = (((i * 4 + wv) * 64) + lane) * 16;
            int row = o >> 7;
            int p   = (o >> 4) & 7;
            int gr  = m0 + row; gr = gr < M ? gr : M - 1;
            const f16* g = A + (size_t)gr * lda + k0 + ((p ^ (row & 7)) << 3);
            gl2lds16(g, (char*)sA + (i * 4 + wv) * 1024);
        }
#pragma unroll
        for (int i = 0; i < BN / 32; ++i) {
            int o   = (((i * 4 + wv) * 64) + lane) * 16;
            int row = o >> 7;
            int p   = (o >> 4) & 7;
            int gr  = n0 + row; gr = gr < Nb ? gr : Nb - 1;
            const f16* g = B + (size_t)gr * ldb + k0 + ((p ^ (row & 7)) << 3);
            gl2lds16(g, (char*)sB + (i * 4 + wv) * 1024);
        }
        __syncthreads();

        const int rl = lane & 15, cl = lane >> 4;
#pragma unroll
        for (int kh = 0; kh < 2; ++kh) {
            f16x8 af[4], bfr[NF];
#pragma unroll
            for (int mf = 0; mf < 4; ++mf) {
                int row = wm * 64 + mf * 16 + rl;
                int ch  = (kh * 4 + cl) ^ (row & 7);
                af[mf]  = *(const f16x8*)&sA[row * 64 + ch * 8];
            }
#pragma unroll
            for (int nf = 0; nf < NF; ++nf) {
                int row = wn * (BN / 2) + nf * 16 + rl;
                int ch  = (kh * 4 + cl) ^ (row & 7);
                bfr[nf] = *(const f16x8*)&sB[row * 64 + ch * 8];
            }
#pragma unroll
            for (int mf = 0; mf < 4; ++mf)
#pragma unroll
                for (int nf = 0; nf < NF; ++nf)
                    acc[mf][nf] = __builtin_amdgcn_mfma_f32_16x16x32_f16(
                        af[mf], bfr[nf], acc[mf][nf], 0, 0, 0);
        }
    }

    const int rl = lane & 15, cl = lane >> 4;
#pragma unroll
    for (int mf = 0; mf < 4; ++mf) {
#pragma unroll
        for (int r = 0; r < 4; ++r) {
            int gm = m0 + wm * 64 + mf * 16 + cl * 4 + r;
            if (gm >= M) continue;
#pragma unroll
            for (int nf = 0; nf < NF; ++nf) {
                int gn = n0 + wn * (BN / 2) + nf * 16 + rl;
                if (gn >= ldc) continue;
                float v = acc[mf][nf][r];
                size_t ci = (size_t)gm * ldc + gn;
                if (EPI == 0) {
                    Cf[ci] = v;
                } else if (EPI == 1) {
                    Ch[ci] = (f16)v;
                } else if (EPI == 2) {
                    Ch[ci] = (f16)v;
                    out2[ci] = (f16)fmaxf(v, 0.f);
                } else if (EPI == 3) {
                    v += (float)resid[ci];
                    Ch[ci] = (f16)fmaxf(v, 0.f);
                } else if (EPI == 4) {
                    v += Cf[ci];
                    v += (gn < HID) ? bias[gn] : 0.f;
                    v = fmaxf(v, 0.f);
                    Cf[ci] = v; Ch[ci] = (f16)v;
                } else {
                    v += (gn < HID) ? bias[gn] : 0.f;
                    Cf[ci] = fmaxf(v, 0.f);
                }
            }
        }
    }
}

// ---------------------------------------------------------------------------
// Fused score/softmax/comp, all 4 heads; nei rows gathered ONCE per bond and
// held across heads (256-thr kernel, no launch-bounds cap -> no spill).
// 16 bonds/block x 16 threads; thread owns 20 cols. comp overwrites mt.
// ---------------------------------------------------------------------------
__global__ __launch_bounds__(256) void score_comp_k(
    const f16* __restrict__ msg,     // [E][320] f16
    f16* __restrict__ mtc,           // [E][1280] f16: in mt, out comp
    const int* __restrict__ bgraph)
{
    const int tid = threadIdx.x;
    const int e   = blockIdx.x * 16 + (tid >> 4);
    const int t   = tid & 15;

    u32 nei[KNB][10];
#pragma unroll
    for (int k = 0; k < KNB; ++k) {
        int nb = bgraph[e * KNB + k];
        const u32* p = (const u32*)(msg + (size_t)nb * HP) + t * 10;
#pragma unroll
        for (int j = 0; j < 10; ++j) nei[k][j] = p[j];
    }

    for (int n = 0; n < NH; ++n) {
        u32* mrow = (u32*)(mtc + (size_t)e * (NH * HP) + n * HP) + t * 10;
        u32 mt[10];
#pragma unroll
        for (int j = 0; j < 10; ++j) mt[j] = mrow[j];

        float pk[KNB] = {0.f, 0.f, 0.f, 0.f, 0.f, 0.f};
#pragma unroll
        for (int j = 0; j < 10; ++j) {
            float m0 = hlo(mt[j]), m1 = hhi(mt[j]);
#pragma unroll
            for (int k = 0; k < KNB; ++k)
                pk[k] += hlo(nei[k][j]) * m0 + hhi(nei[k][j]) * m1;
        }
#pragma unroll
        for (int s = 1; s < 16; s <<= 1)
#pragma unroll
            for (int k = 0; k < KNB; ++k) pk[k] += __shfl_xor(pk[k], s);

        float mx = pk[0];
#pragma unroll
        for (int k = 1; k < KNB; ++k) mx = fmaxf(mx, pk[k]);
        float w[KNB], sum = 0.f;
#pragma unroll
        for (int k = 0; k < KNB; ++k) { w[k] = __expf(pk[k] - mx); sum += w[k]; }
        float inv = 1.f / sum;
#pragma unroll
        for (int k = 0; k < KNB; ++k) w[k] *= inv;

#pragma unroll
        for (int j = 0; j < 10; ++j) {
            float c0 = 0.f, c1 = 0.f;
#pragma unroll
            for (int k = 0; k < KNB; ++k) {
                c0 += w[k] * hlo(nei[k][j]);
                c1 += w[k] * hhi(nei[k][j]);
            }
            mrow[j] = packh2(c0, c1);
        }
    }
}

// ---------------------------------------------------------------------------
// a_nei[a] = sum_k msg[agraph[a][k]]
// ---------------------------------------------------------------------------
__global__ void gather_sum_h_k(const f16* __restrict__ msg,
                               const int* __restrict__ agraph,
                               f16* __restrict__ out) {
    int idx = blockIdx.x * 256 + threadIdx.x;
    if (idx >= NATOMS * (HP / 2)) return;
    int a = idx / (HP / 2), c = idx - a * (HP / 2);
    const int* g = agraph + (size_t)a * KNB;
    float s0 = 0.f, s1 = 0.f;
#pragma unroll
    for (int k = 0; k < KNB; ++k) {
        u32 u = *(const u32*)(msg + (size_t)g[k] * HP + c * 2);
        s0 += hlo(u); s1 += hhi(u);
    }
    ((u32*)out)[idx] = packh2(s0, s1);
}

// ---------------------------------------------------------------------------
__global__ void conv_pad_k(const float* __restrict__ src, f16* __restrict__ dst,
                           int R, int C, int CP) {
    int idx = blockIdx.x * 256 + threadIdx.x;
    if (idx >= R * CP) return;
    int r = idx / CP, c = idx - r * CP;
    dst[idx] = (f16)(c < C ? src[(size_t)r * C + c] : 0.f);
}

// ---------------------------------------------------------------------------
// Weight prep -> f16, padded, K-contiguous ([N][K]) layouts.
// mode 0: WiT[320][192]  <- W_i[300][158]
// mode 1: WmaT[1280][320]<- W_ma[n][h][d] at row n*320+d, col h
// mode 2: WhT[320][1280] <- W_h[h_out][n*300+d] at row h_out, col n*320+d
// mode 3: WoA[320][192]  <- W_o cols 0..143
// mode 4: WoB[320][320]  <- W_o cols 144..443
// else:   [320][320]     <- [300][300]
// ---------------------------------------------------------------------------
__global__ void prep_w_k(const float* __restrict__ src, f16* __restrict__ dst,
                         int mode, int R, int CK) {
    int idx = blockIdx.x * 256 + threadIdx.x;
    if (idx >= R * CK) return;
    int r = idx / CK, c = idx - r * CK;
    float v = 0.f;
    if (mode == 0) {
        if (r < HID && c < BONDIN) v = src[r * BONDIN + c];
    } else if (mode == 1) {
        int n = r / HP, d = r - n * HP;
        if (d < HID && c < HID) v = src[((size_t)n * HID + c) * HID + d];
    } else if (mode == 2) {
        int n = c / HP, d = c - n * HP;
        if (r < HID && d < HID) v = src[(size_t)r * (NH * HID) + n * HID + d];
    } else if (mode == 3) {
        if (r < HID && c < AFD) v = src[r * (AFD + HID) + c];
    } else if (mode == 4) {
        if (r < HID && c < HID) v = src[r * (AFD + HID) + AFD + c];
    } else {
        if (r < HID && c < HID) v = src[r * HID + c];
    }
    dst[idx] = (f16)v;
}

// ---------------------------------------------------------------------------
// MFMA molecule attention (proven round 4).
// ---------------------------------------------------------------------------
__global__ __launch_bounds__(256) void mol_attn_mfma_k(
    const f16* __restrict__ atomHh,
    const f16* __restrict__ ah2h,
    f16* __restrict__ comp2h)
{
    __shared__ f16 sCur[64 * 320];
    __shared__ float sP[64][66];
    const int tid  = threadIdx.x;
    const int lane = tid & 63;
    const int wv   = tid >> 6;
    const int m    = blockIdx.x;
    const int rl   = lane & 15, cl = lane >> 4;

#pragma unroll
    for (int i = 0; i < 10; ++i) {
        int g   = i * 256 + wv * 64 + lane;
        int row = g / 40, c = g - row * 40;
        int grow = m * APM + row; grow = grow < NATOMS ? grow : NATOMS - 1;
        const f16* src = atomHh + (size_t)grow * HP + ((c ^ (row & 7)) << 3);
        gl2lds16(src, (char*)sCur + (size_t)(i * 256 + wv * 64) * 16);
    }
    __syncthreads();

    f32x4 acc[4];
#pragma unroll
    for (int nf = 0; nf < 4; ++nf) acc[nf] = (f32x4){0.f, 0.f, 0.f, 0.f};
    int qrow = m * APM + wv * 16 + rl;
    qrow = qrow < NATOMS ? qrow : NATOMS - 1;
    const f16* qbase = ah2h + (size_t)qrow * HP;
#pragma unroll
    for (int kh = 0; kh < 10; ++kh) {
        f16x8 aq = *(const f16x8*)(qbase + kh * 32 + cl * 8);
#pragma unroll
        for (int nf = 0; nf < 4; ++nf) {
            int brow = nf * 16 + rl;
            int ch   = (kh * 4 + cl) ^ (brow & 7);
            f16x8 bv = *(const f16x8*)&sCur[brow * 320 + ch * 8];
            acc[nf] = __builtin_amdgcn_mfma_f32_16x16x32_f16(aq, bv, acc[nf], 0, 0, 0);
        }
    }

#pragma unroll
    for (int r = 0; r < 4; ++r) {
        float s[4];
#pragma unroll
        for (int nf = 0; nf < 4; ++nf) {
            s[nf] = acc[nf][r];
            if (nf == 3 && rl >= 2) s[nf] = -1e30f;
        }
        float mx = fmaxf(fmaxf(s[0], s[1]), fmaxf(s[2], s[3]));
#pragma unroll
        for (int msk = 1; msk < 16; msk <<= 1) mx = fmaxf(mx, __shfl_xor(mx, msk));
        float e[4], sum = 0.f;
#pragma unroll
        for (int nf = 0; nf < 4; ++nf) { e[nf] = __expf(s[nf] - mx); sum += e[nf]; }
#pragma unroll
        for (int msk = 1; msk < 16; msk <<= 1) sum += __shfl_xor(sum, msk);
        float inv = 1.f / sum;
        int a = wv * 16 + cl * 4 + r;
#pragma unroll
        for (int nf = 0; nf < 4; ++nf) sP[a][nf * 16 + rl] = e[nf] * inv;
    }
    __syncthreads();

    const int a  = tid >> 2, hq = tid & 3;
    const bool aval = a < APM;
    const size_t orow = (size_t)(m * APM + a) * HP;
#pragma unroll
    for (int p = 0; p < 2; ++p) {
        float av[40];
#pragma unroll
        for (int i = 0; i < 40; ++i) av[i] = 0.f;
        const int ch0 = p * 20 + hq * 5;
        for (int b = 0; b < APM; ++b) {
            float w = sP[a][b];
#pragma unroll
            for (int i = 0; i < 5; ++i) {
                int ch = (ch0 + i) ^ (b & 7);
                f16x8 cv = *(const f16x8*)&sCur[b * 320 + ch * 8];
#pragma unroll
                for (int j = 0; j < 8; ++j) av[i * 8 + j] += w * (float)cv[j];
            }
        }
        if (aval) {
#pragma unroll
            for (int i = 0; i < 5; ++i) {
                f16x8 o;
#pragma unroll
                for (int j = 0; j < 8; ++j) o[j] = (f16)av[i * 8 + j];
                *(f16x8*)&comp2h[orow + p * 160 + hq * 40 + i * 8] = o;
            }
        }
    }
}

__global__ void mol_reduce_k(const float* __restrict__ atomH,
                             const float* __restrict__ atth,
                             float* __restrict__ out) {
    const int m = blockIdx.x;
    for (int h = threadIdx.x; h < HID; h += 256) {
        float s = 0.f;
        for (int a = 0; a < APM; ++a) {
            size_t i = (size_t)(m * APM + a) * HP + h;
            s += atomH[i] + atth[i];
        }
        out[(size_t)m * HID + h] = s * (1.f / APM);
    }
}

// ---------------------------------------------------------------------------
extern "C" void kernel_launch(void* const* d_in, const int* in_sizes, int n_in,
                              void* d_out, int out_size, void* d_ws, size_t ws_size,
                              hipStream_t stream) {
    const float* fatoms = (const float*)d_in[0];
    const float* fbonds = (const float*)d_in[1];
    const int*   agraph = (const int*)d_in[2];
    const int*   bgraph = (const int*)d_in[3];
    const float* W_i    = (const float*)d_in[4];
    const float* W_ma   = (const float*)d_in[5];
    const float* W_h    = (const float*)d_in[6];
    const float* W_o    = (const float*)d_in[7];
    const float* b_o    = (const float*)d_in[8];
    const float* W_a    = (const float*)d_in[9];
    const float* W_b    = (const float*)d_in[10];
    const float* b_b    = (const float*)d_in[11];
    float* out = (float*)d_out;

    // ---- workspace layout (round-4 proven) ----
    char* ws = (char*)d_ws;
    f16* fbondsh = (f16*)ws;
    f16* mtall   = (f16*)ws;
    f16* aneih   = (f16*)ws;                         // [30000][320] f16
    f16* fatomsh = (f16*)(ws + 19200000);            // [30000][192] f16
    float* atomH = (float*)(ws + 30720000);          // [30000][320] f32
    f16* atomHh  = (f16*)(ws + 69120000);            // [30000][320] f16
    f16* ah2h    = (f16*)(ws + 88320000);            // [30000][320] f16
    f16* comp2h  = (f16*)(ws + 126720000);           // [30000][320] f16
    f16* binh    = (f16*)(ws + 153600000);
    float* atth  = (float*)(ws + 153600000);
    f16* msgh    = (f16*)(ws + 192000000);
    char* wb = ws + 230400000;
    f16* WiT  = (f16*)(wb);
    f16* WmaT = (f16*)(wb + 122880);
    f16* WhT  = (f16*)(wb + 942080);
    f16* WoA  = (f16*)(wb + 1761280);
    f16* WoB  = (f16*)(wb + 1884160);
    f16* Wa   = (f16*)(wb + 2088960);
    f16* Wb   = (f16*)(wb + 2293760);

    // ---- weight/input prep ----
    prep_w_k<<<dim3((320 * 192 + 255) / 256), dim3(256), 0, stream>>>(W_i, WiT, 0, 320, 192);
    prep_w_k<<<dim3((1280 * 320 + 255) / 256), dim3(256), 0, stream>>>(W_ma, WmaT, 1, 1280, 320);
    prep_w_k<<<dim3((320 * 1280 + 255) / 256), dim3(256), 0, stream>>>(W_h, WhT, 2, 320, 1280);
    prep_w_k<<<dim3((320 * 192 + 255) / 256), dim3(256), 0, stream>>>(W_o, WoA, 3, 320, 192);
    prep_w_k<<<dim3((320 * 320 + 255) / 256), dim3(256), 0, stream>>>(W_o, WoB, 4, 320, 320);
    prep_w_k<<<dim3((320 * 320 + 255) / 256), dim3(256), 0, stream>>>(W_a, Wa, 5, 320, 320);
    prep_w_k<<<dim3((320 * 320 + 255) / 256), dim3(256), 0, stream>>>(W_b, Wb, 6, 320, 320);
    conv_pad_k<<<dim3((E_BONDS * 192 + 255) / 256), dim3(256), 0, stream>>>(
        fbonds, fbondsh, E_BONDS, BONDIN, 192);

    // ---- binput/message0 (N=320 exact with BN=160 x2) ----
    mfma_gemm_k<160, 2><<<dim3(469, 2), dim3(256), 0, stream>>>(
        fbondsh, 192, WiT, 192, E_BONDS, 320, 192, HP, nullptr, binh, nullptr, nullptr, msgh);

    // ---- 3 message-passing iterations (split pipeline, round-4 proven) ----
    for (int it = 0; it < 3; ++it) {
        // mt_all = msg @ WmaT^T  (N=1280 exact with BN=256 x5)
        mfma_gemm_k<256, 1><<<dim3(469, 5), dim3(256), 0, stream>>>(
            msgh, HP, WmaT, HP, E_BONDS, NH * HP, HP, NH * HP, nullptr, mtall, nullptr, nullptr, nullptr);
        score_comp_k<<<dim3(E_BONDS / 16), dim3(256), 0, stream>>>(msgh, mtall, bgraph);
        // msg = relu(binput + comp_all @ WhT^T)  (K=1280, N=320 exact)
        mfma_gemm_k<160, 3><<<dim3(469, 2), dim3(256), 0, stream>>>(
            mtall, NH * HP, WhT, NH * HP, E_BONDS, HP, NH * HP, HP, nullptr, msgh, nullptr, binh, nullptr);
    }

    // ---- atom stage ----
    gather_sum_h_k<<<dim3((NATOMS * 160 + 255) / 256), dim3(256), 0, stream>>>(msgh, agraph, aneih);
    conv_pad_k<<<dim3((NATOMS * 192 + 255) / 256), dim3(256), 0, stream>>>(
        fatoms, fatomsh, NATOMS, AFD, 192);
    mfma_gemm_k<160, 0><<<dim3(235, 2), dim3(256), 0, stream>>>(
        fatomsh, 192, WoA, 192, NATOMS, 320, 192, HP, atomH, nullptr, nullptr, nullptr, nullptr);
    mfma_gemm_k<160, 4><<<dim3(235, 2), dim3(256), 0, stream>>>(
        aneih, HP, WoB, HP, NATOMS, 320, HP, HP, atomH, atomHh, b_o, nullptr, nullptr);

    // ---- molecule attention ----
    mfma_gemm_k<160, 1><<<dim3(235, 2), dim3(256), 0, stream>>>(
        atomHh, HP, Wa, HP, NATOMS, 320, HP, HP, nullptr, ah2h, nullptr, nullptr, nullptr);
    mol_attn_mfma_k<<<dim3(NMOLS), dim3(256), 0, stream>>>(atomHh, ah2h, comp2h);
    mfma_gemm_k<160, 5><<<dim3(235, 2), dim3(256), 0, stream>>>(
        comp2h, HP, Wb, HP, NATOMS, 320, HP, HP, atth, nullptr, b_b, nullptr, nullptr);
    mol_reduce_k<<<dim3(NMOLS), dim3(256), 0, stream>>>(atomH, atth, out);
}

// Round 11
// 1100.485 us; speedup vs baseline: 1.9659x; 1.2143x over previous
//
#include <hip/hip_runtime.h>
#include <hip/hip_bf16.h>
#include <math.h>

// Problem constants
#define HID       300
#define HP        320
#define NH        4
#define E_BONDS   60000
#define NATOMS    30000
#define KNB       6
#define NMOLS     600
#define APM       50
#define AFD       144
#define BONDIN    158

typedef unsigned short u16;
typedef unsigned int   u32;
typedef _Float16 f16;
typedef f16   f16x8 __attribute__((ext_vector_type(8)));
typedef float f32x4 __attribute__((ext_vector_type(4)));

// ---------------- helpers ----------------
__device__ inline float hlo(u32 u) { union { u32 i; f16 h[2]; } c; c.i = u; return (float)c.h[0]; }
__device__ inline float hhi(u32 u) { union { u32 i; f16 h[2]; } c; c.i = u; return (float)c.h[1]; }
__device__ inline u32 packh2(float a, float b) {
    union { u32 i; f16 h[2]; } c; c.h[0] = (f16)a; c.h[1] = (f16)b; return c.i;
}

__device__ inline void gl2lds16(const void* g, void* l) {
    __builtin_amdgcn_global_load_lds(
        (const __attribute__((address_space(1))) void*)g,
        (__attribute__((address_space(3))) void*)l, 16, 0, 0);
}

// ---------------------------------------------------------------------------
// MFMA GEMM (round-4 geometry: BN=128, 4 waves, 3 waves/SIMD occupancy).
// GRID SWAP: n0 = blockIdx.x (FAST), m0 = blockIdx.y — consecutive blocks
// share the A row-panel, keeping it L2-hot across its grid.x consumers
// (weights/B are <1MB and L2-resident regardless). Launch dim3(Nb_blocks, Mb).
// EPI: 0 Cf=v | 1 Ch=h(v) | 2 Ch=h(v),out2=h(relu v) | 3 v+=resid,relu,Ch
//      4 v+=Cf+bias,relu,Cf&Ch | 5 v+=bias,relu,Cf
// ---------------------------------------------------------------------------
template <int BN, int EPI>
__global__ __launch_bounds__(256) void mfma_gemm_k(
    const f16* __restrict__ A, int lda,
    const f16* __restrict__ B, int ldb,
    int M, int Nb, int K, int ldc,
    float* __restrict__ Cf, f16* __restrict__ Ch,
    const float* __restrict__ bias,
    const f16* __restrict__ resid,
    f16* __restrict__ out2)
{
    constexpr int NF = BN / 32;
    __shared__ f16 sA[128 * 64];
    __shared__ f16 sB[BN * 64];
    const int tid  = threadIdx.x;
    const int lane = tid & 63;
    const int wv   = tid >> 6;
    const int wm   = wv >> 1, wn = wv & 1;
    const int m0   = blockIdx.y * 128, n0 = blockIdx.x * BN;   // grid swap

    f32x4 acc[4][NF];
#pragma unroll
    for (int i = 0; i < 4; ++i)
#pragma unroll
        for (int j = 0; j < NF; ++j) acc[i][j] = (f32x4){0.f, 0.f, 0.f, 0.f};

    for (int k0 = 0; k0 < K; k0 += 64) {
        __syncthreads();
#pragma unroll
        for (int i = 0; i < 4; ++i) {
            int o   = (((i * 4 + wv) * 64) + lane) * 16;
            int row = o >> 7;
            int p   = (o >> 4) & 7;
            int gr  = m0 + row; gr = gr < M ? gr : M - 1;
            const f16* g = A + (size_t)gr * lda + k0 + ((p ^ (row & 7)) << 3);
            gl2lds16(g, (char*)sA + (i * 4 + wv) * 1024);
        }
#pragma unroll
        for (int i = 0; i < BN / 32; ++i) {
            int o   = (((i * 4 + wv) * 64) + lane) * 16;
            int row = o >> 7;
            int p   = (o >> 4) & 7;
            int gr  = n0 + row; gr = gr < Nb ? gr : Nb - 1;
            const f16* g = B + (size_t)gr * ldb + k0 + ((p ^ (row & 7)) << 3);
            gl2lds16(g, (char*)sB + (i * 4 + wv) * 1024);
        }
        __syncthreads();

        const int rl = lane & 15, cl = lane >> 4;
#pragma unroll
        for (int kh = 0; kh < 2; ++kh) {
            f16x8 af[4], bfr[NF];
#pragma unroll
            for (int mf = 0; mf < 4; ++mf) {
                int row = wm * 64 + mf * 16 + rl;
                int ch  = (kh * 4 + cl) ^ (row & 7);
                af[mf]  = *(const f16x8*)&sA[row * 64 + ch * 8];
            }
#pragma unroll
            for (int nf = 0; nf < NF; ++nf) {
                int row = wn * (BN / 2) + nf * 16 + rl;
                int ch  = (kh * 4 + cl) ^ (row & 7);
                bfr[nf] = *(const f16x8*)&sB[row * 64 + ch * 8];
            }
#pragma unroll
            for (int mf = 0; mf < 4; ++mf)
#pragma unroll
                for (int nf = 0; nf < NF; ++nf)
                    acc[mf][nf] = __builtin_amdgcn_mfma_f32_16x16x32_f16(
                        af[mf], bfr[nf], acc[mf][nf], 0, 0, 0);
        }
    }

    const int rl = lane & 15, cl = lane >> 4;
#pragma unroll
    for (int mf = 0; mf < 4; ++mf) {
#pragma unroll
        for (int r = 0; r < 4; ++r) {
            int gm = m0 + wm * 64 + mf * 16 + cl * 4 + r;
            if (gm >= M) continue;
#pragma unroll
            for (int nf = 0; nf < NF; ++nf) {
                int gn = n0 + wn * (BN / 2) + nf * 16 + rl;
                if (gn >= ldc) continue;
                float v = acc[mf][nf][r];
                size_t ci = (size_t)gm * ldc + gn;
                if (EPI == 0) {
                    Cf[ci] = v;
                } else if (EPI == 1) {
                    Ch[ci] = (f16)v;
                } else if (EPI == 2) {
                    Ch[ci] = (f16)v;
                    out2[ci] = (f16)fmaxf(v, 0.f);
                } else if (EPI == 3) {
                    v += (float)resid[ci];
                    Ch[ci] = (f16)fmaxf(v, 0.f);
                } else if (EPI == 4) {
                    v += Cf[ci];
                    v += (gn < HID) ? bias[gn] : 0.f;
                    v = fmaxf(v, 0.f);
                    Cf[ci] = v; Ch[ci] = (f16)v;
                } else {
                    v += (gn < HID) ? bias[gn] : 0.f;
                    Cf[ci] = fmaxf(v, 0.f);
                }
            }
        }
    }
}

// ---------------------------------------------------------------------------
// Fused score/softmax/comp, all 4 heads; nei gathered once per bond, held
// across heads (256-thr kernel, no spill — round-4 proven).
// ---------------------------------------------------------------------------
__global__ __launch_bounds__(256) void score_comp_k(
    const f16* __restrict__ msg,     // [E][320] f16
    f16* __restrict__ mtc,           // [E][1280] f16: in mt, out comp
    const int* __restrict__ bgraph)
{
    const int tid = threadIdx.x;
    const int e   = blockIdx.x * 16 + (tid >> 4);
    const int t   = tid & 15;

    u32 nei[KNB][10];
#pragma unroll
    for (int k = 0; k < KNB; ++k) {
        int nb = bgraph[e * KNB + k];
        const u32* p = (const u32*)(msg + (size_t)nb * HP) + t * 10;
#pragma unroll
        for (int j = 0; j < 10; ++j) nei[k][j] = p[j];
    }

    for (int n = 0; n < NH; ++n) {
        u32* mrow = (u32*)(mtc + (size_t)e * (NH * HP) + n * HP) + t * 10;
        u32 mt[10];
#pragma unroll
        for (int j = 0; j < 10; ++j) mt[j] = mrow[j];

        float pk[KNB] = {0.f, 0.f, 0.f, 0.f, 0.f, 0.f};
#pragma unroll
        for (int j = 0; j < 10; ++j) {
            float m0 = hlo(mt[j]), m1 = hhi(mt[j]);
#pragma unroll
            for (int k = 0; k < KNB; ++k)
                pk[k] += hlo(nei[k][j]) * m0 + hhi(nei[k][j]) * m1;
        }
#pragma unroll
        for (int s = 1; s < 16; s <<= 1)
#pragma unroll
            for (int k = 0; k < KNB; ++k) pk[k] += __shfl_xor(pk[k], s);

        float mx = pk[0];
#pragma unroll
        for (int k = 1; k < KNB; ++k) mx = fmaxf(mx, pk[k]);
        float w[KNB], sum = 0.f;
#pragma unroll
        for (int k = 0; k < KNB; ++k) { w[k] = __expf(pk[k] - mx); sum += w[k]; }
        float inv = 1.f / sum;
#pragma unroll
        for (int k = 0; k < KNB; ++k) w[k] *= inv;

#pragma unroll
        for (int j = 0; j < 10; ++j) {
            float c0 = 0.f, c1 = 0.f;
#pragma unroll
            for (int k = 0; k < KNB; ++k) {
                c0 += w[k] * hlo(nei[k][j]);
                c1 += w[k] * hhi(nei[k][j]);
            }
            mrow[j] = packh2(c0, c1);
        }
    }
}

// ---------------------------------------------------------------------------
// a_nei[a] = sum_k msg[agraph[a][k]]
// ---------------------------------------------------------------------------
__global__ void gather_sum_h_k(const f16* __restrict__ msg,
                               const int* __restrict__ agraph,
                               f16* __restrict__ out) {
    int idx = blockIdx.x * 256 + threadIdx.x;
    if (idx >= NATOMS * (HP / 2)) return;
    int a = idx / (HP / 2), c = idx - a * (HP / 2);
    const int* g = agraph + (size_t)a * KNB;
    float s0 = 0.f, s1 = 0.f;
#pragma unroll
    for (int k = 0; k < KNB; ++k) {
        u32 u = *(const u32*)(msg + (size_t)g[k] * HP + c * 2);
        s0 += hlo(u); s1 += hhi(u);
    }
    ((u32*)out)[idx] = packh2(s0, s1);
}

// ---------------------------------------------------------------------------
__global__ void conv_pad_k(const float* __restrict__ src, f16* __restrict__ dst,
                           int R, int C, int CP) {
    int idx = blockIdx.x * 256 + threadIdx.x;
    if (idx >= R * CP) return;
    int r = idx / CP, c = idx - r * CP;
    dst[idx] = (f16)(c < C ? src[(size_t)r * C + c] : 0.f);
}

// ---------------------------------------------------------------------------
// Weight prep -> f16, padded, K-contiguous ([N][K]) layouts.
// mode 0: WiT[320][192]  <- W_i[300][158]
// mode 1: WmaT[1280][320]<- W_ma[n][h][d] at row n*320+d, col h
// mode 2: WhT[320][1280] <- W_h[h_out][n*300+d] at row h_out, col n*320+d
// mode 3: WoA[320][192]  <- W_o cols 0..143
// mode 4: WoB[320][320]  <- W_o cols 144..443
// else:   [320][320]     <- [300][300]
// ---------------------------------------------------------------------------
__global__ void prep_w_k(const float* __restrict__ src, f16* __restrict__ dst,
                         int mode, int R, int CK) {
    int idx = blockIdx.x * 256 + threadIdx.x;
    if (idx >= R * CK) return;
    int r = idx / CK, c = idx - r * CK;
    float v = 0.f;
    if (mode == 0) {
        if (r < HID && c < BONDIN) v = src[r * BONDIN + c];
    } else if (mode == 1) {
        int n = r / HP, d = r - n * HP;
        if (d < HID && c < HID) v = src[((size_t)n * HID + c) * HID + d];
    } else if (mode == 2) {
        int n = c / HP, d = c - n * HP;
        if (r < HID && d < HID) v = src[(size_t)r * (NH * HID) + n * HID + d];
    } else if (mode == 3) {
        if (r < HID && c < AFD) v = src[r * (AFD + HID) + c];
    } else if (mode == 4) {
        if (r < HID && c < HID) v = src[r * (AFD + HID) + AFD + c];
    } else {
        if (r < HID && c < HID) v = src[r * HID + c];
    }
    dst[idx] = (f16)v;
}

// ---------------------------------------------------------------------------
// MFMA molecule attention (proven round 4).
// ---------------------------------------------------------------------------
__global__ __launch_bounds__(256) void mol_attn_mfma_k(
    const f16* __restrict__ atomHh,
    const f16* __restrict__ ah2h,
    f16* __restrict__ comp2h)
{
    __shared__ f16 sCur[64 * 320];
    __shared__ float sP[64][66];
    const int tid  = threadIdx.x;
    const int lane = tid & 63;
    const int wv   = tid >> 6;
    const int m    = blockIdx.x;
    const int rl   = lane & 15, cl = lane >> 4;

#pragma unroll
    for (int i = 0; i < 10; ++i) {
        int g   = i * 256 + wv * 64 + lane;
        int row = g / 40, c = g - row * 40;
        int grow = m * APM + row; grow = grow < NATOMS ? grow : NATOMS - 1;
        const f16* src = atomHh + (size_t)grow * HP + ((c ^ (row & 7)) << 3);
        gl2lds16(src, (char*)sCur + (size_t)(i * 256 + wv * 64) * 16);
    }
    __syncthreads();

    f32x4 acc[4];
#pragma unroll
    for (int nf = 0; nf < 4; ++nf) acc[nf] = (f32x4){0.f, 0.f, 0.f, 0.f};
    int qrow = m * APM + wv * 16 + rl;
    qrow = qrow < NATOMS ? qrow : NATOMS - 1;
    const f16* qbase = ah2h + (size_t)qrow * HP;
#pragma unroll
    for (int kh = 0; kh < 10; ++kh) {
        f16x8 aq = *(const f16x8*)(qbase + kh * 32 + cl * 8);
#pragma unroll
        for (int nf = 0; nf < 4; ++nf) {
            int brow = nf * 16 + rl;
            int ch   = (kh * 4 + cl) ^ (brow & 7);
            f16x8 bv = *(const f16x8*)&sCur[brow * 320 + ch * 8];
            acc[nf] = __builtin_amdgcn_mfma_f32_16x16x32_f16(aq, bv, acc[nf], 0, 0, 0);
        }
    }

#pragma unroll
    for (int r = 0; r < 4; ++r) {
        float s[4];
#pragma unroll
        for (int nf = 0; nf < 4; ++nf) {
            s[nf] = acc[nf][r];
            if (nf == 3 && rl >= 2) s[nf] = -1e30f;
        }
        float mx = fmaxf(fmaxf(s[0], s[1]), fmaxf(s[2], s[3]));
#pragma unroll
        for (int msk = 1; msk < 16; msk <<= 1) mx = fmaxf(mx, __shfl_xor(mx, msk));
        float e[4], sum = 0.f;
#pragma unroll
        for (int nf = 0; nf < 4; ++nf) { e[nf] = __expf(s[nf] - mx); sum += e[nf]; }
#pragma unroll
        for (int msk = 1; msk < 16; msk <<= 1) sum += __shfl_xor(sum, msk);
        float inv = 1.f / sum;
        int a = wv * 16 + cl * 4 + r;
#pragma unroll
        for (int nf = 0; nf < 4; ++nf) sP[a][nf * 16 + rl] = e[nf] * inv;
    }
    __syncthreads();

    const int a  = tid >> 2, hq = tid & 3;
    const bool aval = a < APM;
    const size_t orow = (size_t)(m * APM + a) * HP;
#pragma unroll
    for (int p = 0; p < 2; ++p) {
        float av[40];
#pragma unroll
        for (int i = 0; i < 40; ++i) av[i] = 0.f;
        const int ch0 = p * 20 + hq * 5;
        for (int b = 0; b < APM; ++b) {
            float w = sP[a][b];
#pragma unroll
            for (int i = 0; i < 5; ++i) {
                int ch = (ch0 + i) ^ (b & 7);
                f16x8 cv = *(const f16x8*)&sCur[b * 320 + ch * 8];
#pragma unroll
                for (int j = 0; j < 8; ++j) av[i * 8 + j] += w * (float)cv[j];
            }
        }
        if (aval) {
#pragma unroll
            for (int i = 0; i < 5; ++i) {
                f16x8 o;
#pragma unroll
                for (int j = 0; j < 8; ++j) o[j] = (f16)av[i * 8 + j];
                *(f16x8*)&comp2h[orow + p * 160 + hq * 40 + i * 8] = o;
            }
        }
    }
}

__global__ void mol_reduce_k(const float* __restrict__ atomH,
                             const float* __restrict__ atth,
                             float* __restrict__ out) {
    const int m = blockIdx.x;
    for (int h = threadIdx.x; h < HID; h += 256) {
        float s = 0.f;
        for (int a = 0; a < APM; ++a) {
            size_t i = (size_t)(m * APM + a) * HP + h;
            s += atomH[i] + atth[i];
        }
        out[(size_t)m * HID + h] = s * (1.f / APM);
    }
}

// ---------------------------------------------------------------------------
extern "C" void kernel_launch(void* const* d_in, const int* in_sizes, int n_in,
                              void* d_out, int out_size, void* d_ws, size_t ws_size,
                              hipStream_t stream) {
    const float* fatoms = (const float*)d_in[0];
    const float* fbonds = (const float*)d_in[1];
    const int*   agraph = (const int*)d_in[2];
    const int*   bgraph = (const int*)d_in[3];
    const float* W_i    = (const float*)d_in[4];
    const float* W_ma   = (const float*)d_in[5];
    const float* W_h    = (const float*)d_in[6];
    const float* W_o    = (const float*)d_in[7];
    const float* b_o    = (const float*)d_in[8];
    const float* W_a    = (const float*)d_in[9];
    const float* W_b    = (const float*)d_in[10];
    const float* b_b    = (const float*)d_in[11];
    float* out = (float*)d_out;

    // ---- workspace layout (round-4 proven) ----
    char* ws = (char*)d_ws;
    f16* fbondsh = (f16*)ws;
    f16* mtall   = (f16*)ws;
    f16* aneih   = (f16*)ws;                         // [30000][320] f16
    f16* fatomsh = (f16*)(ws + 19200000);            // [30000][192] f16
    float* atomH = (float*)(ws + 30720000);          // [30000][320] f32
    f16* atomHh  = (f16*)(ws + 69120000);            // [30000][320] f16
    f16* ah2h    = (f16*)(ws + 88320000);            // [30000][320] f16
    f16* comp2h  = (f16*)(ws + 126720000);           // [30000][320] f16
    f16* binh    = (f16*)(ws + 153600000);
    float* atth  = (float*)(ws + 153600000);
    f16* msgh    = (f16*)(ws + 192000000);
    char* wb = ws + 230400000;
    f16* WiT  = (f16*)(wb);
    f16* WmaT = (f16*)(wb + 122880);
    f16* WhT  = (f16*)(wb + 942080);
    f16* WoA  = (f16*)(wb + 1761280);
    f16* WoB  = (f16*)(wb + 1884160);
    f16* Wa   = (f16*)(wb + 2088960);
    f16* Wb   = (f16*)(wb + 2293760);

    // ---- weight/input prep ----
    prep_w_k<<<dim3((320 * 192 + 255) / 256), dim3(256), 0, stream>>>(W_i, WiT, 0, 320, 192);
    prep_w_k<<<dim3((1280 * 320 + 255) / 256), dim3(256), 0, stream>>>(W_ma, WmaT, 1, 1280, 320);
    prep_w_k<<<dim3((320 * 1280 + 255) / 256), dim3(256), 0, stream>>>(W_h, WhT, 2, 320, 1280);
    prep_w_k<<<dim3((320 * 192 + 255) / 256), dim3(256), 0, stream>>>(W_o, WoA, 3, 320, 192);
    prep_w_k<<<dim3((320 * 320 + 255) / 256), dim3(256), 0, stream>>>(W_o, WoB, 4, 320, 320);
    prep_w_k<<<dim3((320 * 320 + 255) / 256), dim3(256), 0, stream>>>(W_a, Wa, 5, 320, 320);
    prep_w_k<<<dim3((320 * 320 + 255) / 256), dim3(256), 0, stream>>>(W_b, Wb, 6, 320, 320);
    conv_pad_k<<<dim3((E_BONDS * 192 + 255) / 256), dim3(256), 0, stream>>>(
        fbonds, fbondsh, E_BONDS, BONDIN, 192);

    // ---- binput/message0 (grid = (Nblocks, Mblocks): N fast for L2-hot A) ----
    mfma_gemm_k<128, 2><<<dim3(3, 469), dim3(256), 0, stream>>>(
        fbondsh, 192, WiT, 192, E_BONDS, 320, 192, HP, nullptr, binh, nullptr, nullptr, msgh);

    // ---- 3 message-passing iterations (split pipeline, round-4 proven) ----
    for (int it = 0; it < 3; ++it) {
        // mt_all = msg @ WmaT^T : A-panel (80KB) reused by 10 consecutive blocks
        mfma_gemm_k<128, 1><<<dim3(10, 469), dim3(256), 0, stream>>>(
            msgh, HP, WmaT, HP, E_BONDS, NH * HP, HP, NH * HP, nullptr, mtall, nullptr, nullptr, nullptr);
        score_comp_k<<<dim3(E_BONDS / 16), dim3(256), 0, stream>>>(msgh, mtall, bgraph);
        // msg = relu(binput + comp_all @ WhT^T) : A-panel (320KB) x3 consecutive
        mfma_gemm_k<128, 3><<<dim3(3, 469), dim3(256), 0, stream>>>(
            mtall, NH * HP, WhT, NH * HP, E_BONDS, HP, NH * HP, HP, nullptr, msgh, nullptr, binh, nullptr);
    }

    // ---- atom stage ----
    gather_sum_h_k<<<dim3((NATOMS * 160 + 255) / 256), dim3(256), 0, stream>>>(msgh, agraph, aneih);
    conv_pad_k<<<dim3((NATOMS * 192 + 255) / 256), dim3(256), 0, stream>>>(
        fatoms, fatomsh, NATOMS, AFD, 192);
    mfma_gemm_k<128, 0><<<dim3(3, 235), dim3(256), 0, stream>>>(
        fatomsh, 192, WoA, 192, NATOMS, 320, 192, HP, atomH, nullptr, nullptr, nullptr, nullptr);
    mfma_gemm_k<128, 4><<<dim3(3, 235), dim3(256), 0, stream>>>(
        aneih, HP, WoB, HP, NATOMS, 320, HP, HP, atomH, atomHh, b_o, nullptr, nullptr);

    // ---- molecule attention ----
    mfma_gemm_k<128, 1><<<dim3(3, 235), dim3(256), 0, stream>>>(
        atomHh, HP, Wa, HP, NATOMS, 320, HP, HP, nullptr, ah2h, nullptr, nullptr, nullptr);
    mol_attn_mfma_k<<<dim3(NMOLS), dim3(256), 0, stream>>>(atomHh, ah2h, comp2h);
    mfma_gemm_k<128, 5><<<dim3(3, 235), dim3(256), 0, stream>>>(
        comp2h, HP, Wb, HP, NATOMS, 320, HP, HP, atth, nullptr, b_b, nullptr, nullptr);
    mol_reduce_k<<<dim3(NMOLS), dim3(256), 0, stream>>>(atomH, atth, out);
}

// Round 12
// 1031.065 us; speedup vs baseline: 2.0982x; 1.0673x over previous
//
#include <hip/hip_runtime.h>
#include <hip/hip_bf16.h>
#include <math.h>

// Problem constants
#define HID       300
#define HP        320
#define NH        4
#define E_BONDS   60000
#define NATOMS    30000
#define KNB       6
#define NMOLS     600
#define APM       50
#define AFD       144
#define BONDIN    158

typedef unsigned short u16;
typedef unsigned int   u32;
typedef _Float16 f16;
typedef f16   f16x8 __attribute__((ext_vector_type(8)));
typedef float f32x4 __attribute__((ext_vector_type(4)));

// ---------------- helpers ----------------
__device__ inline float hlo(u32 u) { union { u32 i; f16 h[2]; } c; c.i = u; return (float)c.h[0]; }
__device__ inline float hhi(u32 u) { union { u32 i; f16 h[2]; } c; c.i = u; return (float)c.h[1]; }
__device__ inline u32 packh2(float a, float b) {
    union { u32 i; f16 h[2]; } c; c.h[0] = (f16)a; c.h[1] = (f16)b; return c.i;
}

__device__ inline void gl2lds16(const void* g, void* l) {
    __builtin_amdgcn_global_load_lds(
        (const __attribute__((address_space(1))) void*)g,
        (__attribute__((address_space(3))) void*)l, 16, 0, 0);
}

// ---------------------------------------------------------------------------
// MFMA GEMM (round-4 geometry: BN=128, 4 waves). XCD-AWARE SWIZZLE:
// 1D grid; linear block b -> xcd=b&7, q=b>>3, xb=q%nbx, yb=(q/nbx)*8+xcd.
// All nbx N-blocks of one M-panel share b%8 => same XCD => A-panel fetched
// once into that XCD's L2 (dispatch round-robins linear id over XCDs).
// Launch grid = nbx * 8 * ceil(mby/8); padded tail early-returns.
// EPI: 0 Cf=v | 1 Ch=h(v) | 2 Ch=h(v),out2=h(relu v) | 3 v+=resid,relu,Ch
//      4 v+=Cf+bias,relu,Cf&Ch | 5 v+=bias,relu,Cf
// ---------------------------------------------------------------------------
template <int BN, int EPI>
__global__ __launch_bounds__(256) void mfma_gemm_k(
    const f16* __restrict__ A, int lda,
    const f16* __restrict__ B, int ldb,
    int M, int Nb, int K, int ldc,
    int nbx, int mby,
    float* __restrict__ Cf, f16* __restrict__ Ch,
    const float* __restrict__ bias,
    const f16* __restrict__ resid,
    f16* __restrict__ out2)
{
    constexpr int NF = BN / 32;
    __shared__ f16 sA[128 * 64];
    __shared__ f16 sB[BN * 64];
    const int b    = blockIdx.x;
    const int xcd  = b & 7;
    const int q    = b >> 3;
    const int xb   = q % nbx;
    const int yb   = (q / nbx) * 8 + xcd;
    if (yb >= mby) return;
    const int tid  = threadIdx.x;
    const int lane = tid & 63;
    const int wv   = tid >> 6;
    const int wm   = wv >> 1, wn = wv & 1;
    const int m0   = yb * 128, n0 = xb * BN;

    f32x4 acc[4][NF];
#pragma unroll
    for (int i = 0; i < 4; ++i)
#pragma unroll
        for (int j = 0; j < NF; ++j) acc[i][j] = (f32x4){0.f, 0.f, 0.f, 0.f};

    for (int k0 = 0; k0 < K; k0 += 64) {
        __syncthreads();
#pragma unroll
        for (int i = 0; i < 4; ++i) {
            int o   = (((i * 4 + wv) * 64) + lane) * 16;
            int row = o >> 7;
            int p   = (o >> 4) & 7;
            int gr  = m0 + row; gr = gr < M ? gr : M - 1;
            const f16* g = A + (size_t)gr * lda + k0 + ((p ^ (row & 7)) << 3);
            gl2lds16(g, (char*)sA + (i * 4 + wv) * 1024);
        }
#pragma unroll
        for (int i = 0; i < BN / 32; ++i) {
            int o   = (((i * 4 + wv) * 64) + lane) * 16;
            int row = o >> 7;
            int p   = (o >> 4) & 7;
            int gr  = n0 + row; gr = gr < Nb ? gr : Nb - 1;
            const f16* g = B + (size_t)gr * ldb + k0 + ((p ^ (row & 7)) << 3);
            gl2lds16(g, (char*)sB + (i * 4 + wv) * 1024);
        }
        __syncthreads();

        const int rl = lane & 15, cl = lane >> 4;
#pragma unroll
        for (int kh = 0; kh < 2; ++kh) {
            f16x8 af[4], bfr[NF];
#pragma unroll
            for (int mf = 0; mf < 4; ++mf) {
                int row = wm * 64 + mf * 16 + rl;
                int ch  = (kh * 4 + cl) ^ (row & 7);
                af[mf]  = *(const f16x8*)&sA[row * 64 + ch * 8];
            }
#pragma unroll
            for (int nf = 0; nf < NF; ++nf) {
                int row = wn * (BN / 2) + nf * 16 + rl;
                int ch  = (kh * 4 + cl) ^ (row & 7);
                bfr[nf] = *(const f16x8*)&sB[row * 64 + ch * 8];
            }
#pragma unroll
            for (int mf = 0; mf < 4; ++mf)
#pragma unroll
                for (int nf = 0; nf < NF; ++nf)
                    acc[mf][nf] = __builtin_amdgcn_mfma_f32_16x16x32_f16(
                        af[mf], bfr[nf], acc[mf][nf], 0, 0, 0);
        }
    }

    const int rl = lane & 15, cl = lane >> 4;
#pragma unroll
    for (int mf = 0; mf < 4; ++mf) {
#pragma unroll
        for (int r = 0; r < 4; ++r) {
            int gm = m0 + wm * 64 + mf * 16 + cl * 4 + r;
            if (gm >= M) continue;
#pragma unroll
            for (int nf = 0; nf < NF; ++nf) {
                int gn = n0 + wn * (BN / 2) + nf * 16 + rl;
                if (gn >= ldc) continue;
                float v = acc[mf][nf][r];
                size_t ci = (size_t)gm * ldc + gn;
                if (EPI == 0) {
                    Cf[ci] = v;
                } else if (EPI == 1) {
                    Ch[ci] = (f16)v;
                } else if (EPI == 2) {
                    Ch[ci] = (f16)v;
                    out2[ci] = (f16)fmaxf(v, 0.f);
                } else if (EPI == 3) {
                    v += (float)resid[ci];
                    Ch[ci] = (f16)fmaxf(v, 0.f);
                } else if (EPI == 4) {
                    v += Cf[ci];
                    v += (gn < HID) ? bias[gn] : 0.f;
                    v = fmaxf(v, 0.f);
                    Cf[ci] = v; Ch[ci] = (f16)v;
                } else {
                    v += (gn < HID) ? bias[gn] : 0.f;
                    Cf[ci] = fmaxf(v, 0.f);
                }
            }
        }
    }
}

// grid size helper (host)
static inline int swz_grid(int nbx, int mby) { return nbx * 8 * ((mby + 7) / 8); }

// ---------------------------------------------------------------------------
// Fused score/softmax/comp, all 4 heads; nei gathered once per bond, held
// across heads (256-thr kernel, no spill — round-4 proven).
// ---------------------------------------------------------------------------
__global__ __launch_bounds__(256) void score_comp_k(
    const f16* __restrict__ msg,     // [E][320] f16
    f16* __restrict__ mtc,           // [E][1280] f16: in mt, out comp
    const int* __restrict__ bgraph)
{
    const int tid = threadIdx.x;
    const int e   = blockIdx.x * 16 + (tid >> 4);
    const int t   = tid & 15;

    u32 nei[KNB][10];
#pragma unroll
    for (int k = 0; k < KNB; ++k) {
        int nb = bgraph[e * KNB + k];
        const u32* p = (const u32*)(msg + (size_t)nb * HP) + t * 10;
#pragma unroll
        for (int j = 0; j < 10; ++j) nei[k][j] = p[j];
    }

    for (int n = 0; n < NH; ++n) {
        u32* mrow = (u32*)(mtc + (size_t)e * (NH * HP) + n * HP) + t * 10;
        u32 mt[10];
#pragma unroll
        for (int j = 0; j < 10; ++j) mt[j] = mrow[j];

        float pk[KNB] = {0.f, 0.f, 0.f, 0.f, 0.f, 0.f};
#pragma unroll
        for (int j = 0; j < 10; ++j) {
            float m0 = hlo(mt[j]), m1 = hhi(mt[j]);
#pragma unroll
            for (int k = 0; k < KNB; ++k)
                pk[k] += hlo(nei[k][j]) * m0 + hhi(nei[k][j]) * m1;
        }
#pragma unroll
        for (int s = 1; s < 16; s <<= 1)
#pragma unroll
            for (int k = 0; k < KNB; ++k) pk[k] += __shfl_xor(pk[k], s);

        float mx = pk[0];
#pragma unroll
        for (int k = 1; k < KNB; ++k) mx = fmaxf(mx, pk[k]);
        float w[KNB], sum = 0.f;
#pragma unroll
        for (int k = 0; k < KNB; ++k) { w[k] = __expf(pk[k] - mx); sum += w[k]; }
        float inv = 1.f / sum;
#pragma unroll
        for (int k = 0; k < KNB; ++k) w[k] *= inv;

#pragma unroll
        for (int j = 0; j < 10; ++j) {
            float c0 = 0.f, c1 = 0.f;
#pragma unroll
            for (int k = 0; k < KNB; ++k) {
                c0 += w[k] * hlo(nei[k][j]);
                c1 += w[k] * hhi(nei[k][j]);
            }
            mrow[j] = packh2(c0, c1);
        }
    }
}

// ---------------------------------------------------------------------------
// a_nei[a] = sum_k msg[agraph[a][k]]
// ---------------------------------------------------------------------------
__global__ void gather_sum_h_k(const f16* __restrict__ msg,
                               const int* __restrict__ agraph,
                               f16* __restrict__ out) {
    int idx = blockIdx.x * 256 + threadIdx.x;
    if (idx >= NATOMS * (HP / 2)) return;
    int a = idx / (HP / 2), c = idx - a * (HP / 2);
    const int* g = agraph + (size_t)a * KNB;
    float s0 = 0.f, s1 = 0.f;
#pragma unroll
    for (int k = 0; k < KNB; ++k) {
        u32 u = *(const u32*)(msg + (size_t)g[k] * HP + c * 2);
        s0 += hlo(u); s1 += hhi(u);
    }
    ((u32*)out)[idx] = packh2(s0, s1);
}

// ---------------------------------------------------------------------------
__global__ void conv_pad_k(const float* __restrict__ src, f16* __restrict__ dst,
                           int R, int C, int CP) {
    int idx = blockIdx.x * 256 + threadIdx.x;
    if (idx >= R * CP) return;
    int r = idx / CP, c = idx - r * CP;
    dst[idx] = (f16)(c < C ? src[(size_t)r * C + c] : 0.f);
}

// ---------------------------------------------------------------------------
// Weight prep -> f16, padded, K-contiguous ([N][K]) layouts.
// mode 0: WiT[320][192]  <- W_i[300][158]
// mode 1: WmaT[1280][320]<- W_ma[n][h][d] at row n*320+d, col h
// mode 2: WhT[320][1280] <- W_h[h_out][n*300+d] at row h_out, col n*320+d
// mode 3: WoA[320][192]  <- W_o cols 0..143
// mode 4: WoB[320][320]  <- W_o cols 144..443
// else:   [320][320]     <- [300][300]
// ---------------------------------------------------------------------------
__global__ void prep_w_k(const float* __restrict__ src, f16* __restrict__ dst,
                         int mode, int R, int CK) {
    int idx = blockIdx.x * 256 + threadIdx.x;
    if (idx >= R * CK) return;
    int r = idx / CK, c = idx - r * CK;
    float v = 0.f;
    if (mode == 0) {
        if (r < HID && c < BONDIN) v = src[r * BONDIN + c];
    } else if (mode == 1) {
        int n = r / HP, d = r - n * HP;
        if (d < HID && c < HID) v = src[((size_t)n * HID + c) * HID + d];
    } else if (mode == 2) {
        int n = c / HP, d = c - n * HP;
        if (r < HID && d < HID) v = src[(size_t)r * (NH * HID) + n * HID + d];
    } else if (mode == 3) {
        if (r < HID && c < AFD) v = src[r * (AFD + HID) + c];
    } else if (mode == 4) {
        if (r < HID && c < HID) v = src[r * (AFD + HID) + AFD + c];
    } else {
        if (r < HID && c < HID) v = src[r * HID + c];
    }
    dst[idx] = (f16)v;
}

// ---------------------------------------------------------------------------
// MFMA molecule attention (proven round 4).
// ---------------------------------------------------------------------------
__global__ __launch_bounds__(256) void mol_attn_mfma_k(
    const f16* __restrict__ atomHh,
    const f16* __restrict__ ah2h,
    f16* __restrict__ comp2h)
{
    __shared__ f16 sCur[64 * 320];
    __shared__ float sP[64][66];
    const int tid  = threadIdx.x;
    const int lane = tid & 63;
    const int wv   = tid >> 6;
    const int m    = blockIdx.x;
    const int rl   = lane & 15, cl = lane >> 4;

#pragma unroll
    for (int i = 0; i < 10; ++i) {
        int g   = i * 256 + wv * 64 + lane;
        int row = g / 40, c = g - row * 40;
        int grow = m * APM + row; grow = grow < NATOMS ? grow : NATOMS - 1;
        const f16* src = atomHh + (size_t)grow * HP + ((c ^ (row & 7)) << 3);
        gl2lds16(src, (char*)sCur + (size_t)(i * 256 + wv * 64) * 16);
    }
    __syncthreads();

    f32x4 acc[4];
#pragma unroll
    for (int nf = 0; nf < 4; ++nf) acc[nf] = (f32x4){0.f, 0.f, 0.f, 0.f};
    int qrow = m * APM + wv * 16 + rl;
    qrow = qrow < NATOMS ? qrow : NATOMS - 1;
    const f16* qbase = ah2h + (size_t)qrow * HP;
#pragma unroll
    for (int kh = 0; kh < 10; ++kh) {
        f16x8 aq = *(const f16x8*)(qbase + kh * 32 + cl * 8);
#pragma unroll
        for (int nf = 0; nf < 4; ++nf) {
            int brow = nf * 16 + rl;
            int ch   = (kh * 4 + cl) ^ (brow & 7);
            f16x8 bv = *(const f16x8*)&sCur[brow * 320 + ch * 8];
            acc[nf] = __builtin_amdgcn_mfma_f32_16x16x32_f16(aq, bv, acc[nf], 0, 0, 0);
        }
    }

#pragma unroll
    for (int r = 0; r < 4; ++r) {
        float s[4];
#pragma unroll
        for (int nf = 0; nf < 4; ++nf) {
            s[nf] = acc[nf][r];
            if (nf == 3 && rl >= 2) s[nf] = -1e30f;
        }
        float mx = fmaxf(fmaxf(s[0], s[1]), fmaxf(s[2], s[3]));
#pragma unroll
        for (int msk = 1; msk < 16; msk <<= 1) mx = fmaxf(mx, __shfl_xor(mx, msk));
        float e[4], sum = 0.f;
#pragma unroll
        for (int nf = 0; nf < 4; ++nf) { e[nf] = __expf(s[nf] - mx); sum += e[nf]; }
#pragma unroll
        for (int msk = 1; msk < 16; msk <<= 1) sum += __shfl_xor(sum, msk);
        float inv = 1.f / sum;
        int a = wv * 16 + cl * 4 + r;
#pragma unroll
        for (int nf = 0; nf < 4; ++nf) sP[a][nf * 16 + rl] = e[nf] * inv;
    }
    __syncthreads();

    const int a  = tid >> 2, hq = tid & 3;
    const bool aval = a < APM;
    const size_t orow = (size_t)(m * APM + a) * HP;
#pragma unroll
    for (int p = 0; p < 2; ++p) {
        float av[40];
#pragma unroll
        for (int i = 0; i < 40; ++i) av[i] = 0.f;
        const int ch0 = p * 20 + hq * 5;
        for (int b = 0; b < APM; ++b) {
            float w = sP[a][b];
#pragma unroll
            for (int i = 0; i < 5; ++i) {
                int ch = (ch0 + i) ^ (b & 7);
                f16x8 cv = *(const f16x8*)&sCur[b * 320 + ch * 8];
#pragma unroll
                for (int j = 0; j < 8; ++j) av[i * 8 + j] += w * (float)cv[j];
            }
        }
        if (aval) {
#pragma unroll
            for (int i = 0; i < 5; ++i) {
                f16x8 o;
#pragma unroll
                for (int j = 0; j < 8; ++j) o[j] = (f16)av[i * 8 + j];
                *(f16x8*)&comp2h[orow + p * 160 + hq * 40 + i * 8] = o;
            }
        }
    }
}

__global__ void mol_reduce_k(const float* __restrict__ atomH,
                             const float* __restrict__ atth,
                             float* __restrict__ out) {
    const int m = blockIdx.x;
    for (int h = threadIdx.x; h < HID; h += 256) {
        float s = 0.f;
        for (int a = 0; a < APM; ++a) {
            size_t i = (size_t)(m * APM + a) * HP + h;
            s += atomH[i] + atth[i];
        }
        out[(size_t)m * HID + h] = s * (1.f / APM);
    }
}

// ---------------------------------------------------------------------------
extern "C" void kernel_launch(void* const* d_in, const int* in_sizes, int n_in,
                              void* d_out, int out_size, void* d_ws, size_t ws_size,
                              hipStream_t stream) {
    const float* fatoms = (const float*)d_in[0];
    const float* fbonds = (const float*)d_in[1];
    const int*   agraph = (const int*)d_in[2];
    const int*   bgraph = (const int*)d_in[3];
    const float* W_i    = (const float*)d_in[4];
    const float* W_ma   = (const float*)d_in[5];
    const float* W_h    = (const float*)d_in[6];
    const float* W_o    = (const float*)d_in[7];
    const float* b_o    = (const float*)d_in[8];
    const float* W_a    = (const float*)d_in[9];
    const float* W_b    = (const float*)d_in[10];
    const float* b_b    = (const float*)d_in[11];
    float* out = (float*)d_out;

    // ---- workspace layout (round-4 proven) ----
    char* ws = (char*)d_ws;
    f16* fbondsh = (f16*)ws;
    f16* mtall   = (f16*)ws;
    f16* aneih   = (f16*)ws;                         // [30000][320] f16
    f16* fatomsh = (f16*)(ws + 19200000);            // [30000][192] f16
    float* atomH = (float*)(ws + 30720000);          // [30000][320] f32
    f16* atomHh  = (f16*)(ws + 69120000);            // [30000][320] f16
    f16* ah2h    = (f16*)(ws + 88320000);            // [30000][320] f16
    f16* comp2h  = (f16*)(ws + 126720000);           // [30000][320] f16
    f16* binh    = (f16*)(ws + 153600000);
    float* atth  = (float*)(ws + 153600000);
    f16* msgh    = (f16*)(ws + 192000000);
    char* wb = ws + 230400000;
    f16* WiT  = (f16*)(wb);
    f16* WmaT = (f16*)(wb + 122880);
    f16* WhT  = (f16*)(wb + 942080);
    f16* WoA  = (f16*)(wb + 1761280);
    f16* WoB  = (f16*)(wb + 1884160);
    f16* Wa   = (f16*)(wb + 2088960);
    f16* Wb   = (f16*)(wb + 2293760);

    // ---- weight/input prep ----
    prep_w_k<<<dim3((320 * 192 + 255) / 256), dim3(256), 0, stream>>>(W_i, WiT, 0, 320, 192);
    prep_w_k<<<dim3((1280 * 320 + 255) / 256), dim3(256), 0, stream>>>(W_ma, WmaT, 1, 1280, 320);
    prep_w_k<<<dim3((320 * 1280 + 255) / 256), dim3(256), 0, stream>>>(W_h, WhT, 2, 320, 1280);
    prep_w_k<<<dim3((320 * 192 + 255) / 256), dim3(256), 0, stream>>>(W_o, WoA, 3, 320, 192);
    prep_w_k<<<dim3((320 * 320 + 255) / 256), dim3(256), 0, stream>>>(W_o, WoB, 4, 320, 320);
    prep_w_k<<<dim3((320 * 320 + 255) / 256), dim3(256), 0, stream>>>(W_a, Wa, 5, 320, 320);
    prep_w_k<<<dim3((320 * 320 + 255) / 256), dim3(256), 0, stream>>>(W_b, Wb, 6, 320, 320);
    conv_pad_k<<<dim3((E_BONDS * 192 + 255) / 256), dim3(256), 0, stream>>>(
        fbonds, fbondsh, E_BONDS, BONDIN, 192);

    // ---- binput/message0 ----
    mfma_gemm_k<128, 2><<<dim3(swz_grid(3, 469)), dim3(256), 0, stream>>>(
        fbondsh, 192, WiT, 192, E_BONDS, 320, 192, HP, 3, 469,
        nullptr, binh, nullptr, nullptr, msgh);

    // ---- 3 message-passing iterations (split pipeline) ----
    for (int it = 0; it < 3; ++it) {
        mfma_gemm_k<128, 1><<<dim3(swz_grid(10, 469)), dim3(256), 0, stream>>>(
            msgh, HP, WmaT, HP, E_BONDS, NH * HP, HP, NH * HP, 10, 469,
            nullptr, mtall, nullptr, nullptr, nullptr);
        score_comp_k<<<dim3(E_BONDS / 16), dim3(256), 0, stream>>>(msgh, mtall, bgraph);
        mfma_gemm_k<128, 3><<<dim3(swz_grid(3, 469)), dim3(256), 0, stream>>>(
            mtall, NH * HP, WhT, NH * HP, E_BONDS, HP, NH * HP, HP, 3, 469,
            nullptr, msgh, nullptr, binh, nullptr);
    }

    // ---- atom stage ----
    gather_sum_h_k<<<dim3((NATOMS * 160 + 255) / 256), dim3(256), 0, stream>>>(msgh, agraph, aneih);
    conv_pad_k<<<dim3((NATOMS * 192 + 255) / 256), dim3(256), 0, stream>>>(
        fatoms, fatomsh, NATOMS, AFD, 192);
    mfma_gemm_k<128, 0><<<dim3(swz_grid(3, 235)), dim3(256), 0, stream>>>(
        fatomsh, 192, WoA, 192, NATOMS, 320, 192, HP, 3, 235,
        atomH, nullptr, nullptr, nullptr, nullptr);
    mfma_gemm_k<128, 4><<<dim3(swz_grid(3, 235)), dim3(256), 0, stream>>>(
        aneih, HP, WoB, HP, NATOMS, 320, HP, HP, 3, 235,
        atomH, atomHh, b_o, nullptr, nullptr);

    // ---- molecule attention ----
    mfma_gemm_k<128, 1><<<dim3(swz_grid(3, 235)), dim3(256), 0, stream>>>(
        atomHh, HP, Wa, HP, NATOMS, 320, HP, HP, 3, 235,
        nullptr, ah2h, nullptr, nullptr, nullptr);
    mol_attn_mfma_k<<<dim3(NMOLS), dim3(256), 0, stream>>>(atomHh, ah2h, comp2h);
    mfma_gemm_k<128, 5><<<dim3(swz_grid(3, 235)), dim3(256), 0, stream>>>(
        comp2h, HP, Wb, HP, NATOMS, 320, HP, HP, 3, 235,
        atth, nullptr, b_b, nullptr, nullptr);
    mol_reduce_k<<<dim3(NMOLS), dim3(256), 0, stream>>>(atomH, atth, out);
}

// Round 13
// 955.187 us; speedup vs baseline: 2.2649x; 1.0794x over previous
//
#include <hip/hip_runtime.h>
#include <hip/hip_bf16.h>
#include <math.h>

// Problem constants
#define HID       300
#define HP        320
#define NH        4
#define E_BONDS   60000
#define NATOMS    30000
#define KNB       6
#define NMOLS     600
#define APM       50
#define AFD       144
#define BONDIN    158

typedef unsigned short u16;
typedef unsigned int   u32;
typedef _Float16 f16;
typedef f16   f16x8 __attribute__((ext_vector_type(8)));
typedef float f32x4 __attribute__((ext_vector_type(4)));

// ---------------- helpers ----------------
__device__ inline float hlo(u32 u) { union { u32 i; f16 h[2]; } c; c.i = u; return (float)c.h[0]; }
__device__ inline float hhi(u32 u) { union { u32 i; f16 h[2]; } c; c.i = u; return (float)c.h[1]; }
__device__ inline u32 packh2(float a, float b) {
    union { u32 i; f16 h[2]; } c; c.h[0] = (f16)a; c.h[1] = (f16)b; return c.i;
}

__device__ inline void gl2lds16(const void* g, void* l) {
    __builtin_amdgcn_global_load_lds(
        (const __attribute__((address_space(1))) void*)g,
        (__attribute__((address_space(3))) void*)l, 16, 0, 0);
}

// ---------------------------------------------------------------------------
// MFMA GEMM (round-4 geometry + XCD swizzle). __launch_bounds__(256,4):
// target 4 blocks/CU => allocator budget 128 regs/wave total (64 arch + 64
// accum). At 144 total (r12) we sat on the wrong side of the 128-reg
// occupancy cliff (8 waves/CU); <=128 doubles residency to 16 waves/CU.
// 1D grid; linear block b -> xcd=b&7, q=b>>3, xb=q%nbx, yb=(q/nbx)*8+xcd.
// EPI: 0 Cf=v | 1 Ch=h(v) | 2 Ch=h(v),out2=h(relu v) | 3 v+=resid,relu,Ch
//      4 v+=Cf+bias,relu,Cf&Ch | 5 v+=bias,relu,Cf
// ---------------------------------------------------------------------------
template <int BN, int EPI>
__global__ __launch_bounds__(256, 4) void mfma_gemm_k(
    const f16* __restrict__ A, int lda,
    const f16* __restrict__ B, int ldb,
    int M, int Nb, int K, int ldc,
    int nbx, int mby,
    float* __restrict__ Cf, f16* __restrict__ Ch,
    const float* __restrict__ bias,
    const f16* __restrict__ resid,
    f16* __restrict__ out2)
{
    constexpr int NF = BN / 32;
    __shared__ f16 sA[128 * 64];
    __shared__ f16 sB[BN * 64];
    const int b    = blockIdx.x;
    const int xcd  = b & 7;
    const int q    = b >> 3;
    const int xb   = q % nbx;
    const int yb   = (q / nbx) * 8 + xcd;
    if (yb >= mby) return;
    const int tid  = threadIdx.x;
    const int lane = tid & 63;
    const int wv   = tid >> 6;
    const int wm   = wv >> 1, wn = wv & 1;
    const int m0   = yb * 128, n0 = xb * BN;

    f32x4 acc[4][NF];
#pragma unroll
    for (int i = 0; i < 4; ++i)
#pragma unroll
        for (int j = 0; j < NF; ++j) acc[i][j] = (f32x4){0.f, 0.f, 0.f, 0.f};

    for (int k0 = 0; k0 < K; k0 += 64) {
        __syncthreads();
#pragma unroll
        for (int i = 0; i < 4; ++i) {
            int o   = (((i * 4 + wv) * 64) + lane) * 16;
            int row = o >> 7;
            int p   = (o >> 4) & 7;
            int gr  = m0 + row; gr = gr < M ? gr : M - 1;
            const f16* g = A + (size_t)gr * lda + k0 + ((p ^ (row & 7)) << 3);
            gl2lds16(g, (char*)sA + (i * 4 + wv) * 1024);
        }
#pragma unroll
        for (int i = 0; i < BN / 32; ++i) {
            int o   = (((i * 4 + wv) * 64) + lane) * 16;
            int row = o >> 7;
            int p   = (o >> 4) & 7;
            int gr  = n0 + row; gr = gr < Nb ? gr : Nb - 1;
            const f16* g = B + (size_t)gr * ldb + k0 + ((p ^ (row & 7)) << 3);
            gl2lds16(g, (char*)sB + (i * 4 + wv) * 1024);
        }
        __syncthreads();

        const int rl = lane & 15, cl = lane >> 4;
#pragma unroll
        for (int kh = 0; kh < 2; ++kh) {
            f16x8 af[4], bfr[NF];
#pragma unroll
            for (int mf = 0; mf < 4; ++mf) {
                int row = wm * 64 + mf * 16 + rl;
                int ch  = (kh * 4 + cl) ^ (row & 7);
                af[mf]  = *(const f16x8*)&sA[row * 64 + ch * 8];
            }
#pragma unroll
            for (int nf = 0; nf < NF; ++nf) {
                int row = wn * (BN / 2) + nf * 16 + rl;
                int ch  = (kh * 4 + cl) ^ (row & 7);
                bfr[nf] = *(const f16x8*)&sB[row * 64 + ch * 8];
            }
#pragma unroll
            for (int mf = 0; mf < 4; ++mf)
#pragma unroll
                for (int nf = 0; nf < NF; ++nf)
                    acc[mf][nf] = __builtin_amdgcn_mfma_f32_16x16x32_f16(
                        af[mf], bfr[nf], acc[mf][nf], 0, 0, 0);
        }
    }

    const int rl = lane & 15, cl = lane >> 4;
#pragma unroll
    for (int mf = 0; mf < 4; ++mf) {
#pragma unroll
        for (int r = 0; r < 4; ++r) {
            int gm = m0 + wm * 64 + mf * 16 + cl * 4 + r;
            if (gm >= M) continue;
#pragma unroll
            for (int nf = 0; nf < NF; ++nf) {
                int gn = n0 + wn * (BN / 2) + nf * 16 + rl;
                if (gn >= ldc) continue;
                float v = acc[mf][nf][r];
                size_t ci = (size_t)gm * ldc + gn;
                if (EPI == 0) {
                    Cf[ci] = v;
                } else if (EPI == 1) {
                    Ch[ci] = (f16)v;
                } else if (EPI == 2) {
                    Ch[ci] = (f16)v;
                    out2[ci] = (f16)fmaxf(v, 0.f);
                } else if (EPI == 3) {
                    v += (float)resid[ci];
                    Ch[ci] = (f16)fmaxf(v, 0.f);
                } else if (EPI == 4) {
                    v += Cf[ci];
                    v += (gn < HID) ? bias[gn] : 0.f;
                    v = fmaxf(v, 0.f);
                    Cf[ci] = v; Ch[ci] = (f16)v;
                } else {
                    v += (gn < HID) ? bias[gn] : 0.f;
                    Cf[ci] = fmaxf(v, 0.f);
                }
            }
        }
    }
}

// grid size helper (host)
static inline int swz_grid(int nbx, int mby) { return nbx * 8 * ((mby + 7) / 8); }

// ---------------------------------------------------------------------------
// Fused score/softmax/comp, all 4 heads; nei gathered once per bond, held
// across heads (256-thr kernel, no spill — round-4 proven).
// ---------------------------------------------------------------------------
__global__ __launch_bounds__(256) void score_comp_k(
    const f16* __restrict__ msg,     // [E][320] f16
    f16* __restrict__ mtc,           // [E][1280] f16: in mt, out comp
    const int* __restrict__ bgraph)
{
    const int tid = threadIdx.x;
    const int e   = blockIdx.x * 16 + (tid >> 4);
    const int t   = tid & 15;

    u32 nei[KNB][10];
#pragma unroll
    for (int k = 0; k < KNB; ++k) {
        int nb = bgraph[e * KNB + k];
        const u32* p = (const u32*)(msg + (size_t)nb * HP) + t * 10;
#pragma unroll
        for (int j = 0; j < 10; ++j) nei[k][j] = p[j];
    }

    for (int n = 0; n < NH; ++n) {
        u32* mrow = (u32*)(mtc + (size_t)e * (NH * HP) + n * HP) + t * 10;
        u32 mt[10];
#pragma unroll
        for (int j = 0; j < 10; ++j) mt[j] = mrow[j];

        float pk[KNB] = {0.f, 0.f, 0.f, 0.f, 0.f, 0.f};
#pragma unroll
        for (int j = 0; j < 10; ++j) {
            float m0 = hlo(mt[j]), m1 = hhi(mt[j]);
#pragma unroll
            for (int k = 0; k < KNB; ++k)
                pk[k] += hlo(nei[k][j]) * m0 + hhi(nei[k][j]) * m1;
        }
#pragma unroll
        for (int s = 1; s < 16; s <<= 1)
#pragma unroll
            for (int k = 0; k < KNB; ++k) pk[k] += __shfl_xor(pk[k], s);

        float mx = pk[0];
#pragma unroll
        for (int k = 1; k < KNB; ++k) mx = fmaxf(mx, pk[k]);
        float w[KNB], sum = 0.f;
#pragma unroll
        for (int k = 0; k < KNB; ++k) { w[k] = __expf(pk[k] - mx); sum += w[k]; }
        float inv = 1.f / sum;
#pragma unroll
        for (int k = 0; k < KNB; ++k) w[k] *= inv;

#pragma unroll
        for (int j = 0; j < 10; ++j) {
            float c0 = 0.f, c1 = 0.f;
#pragma unroll
            for (int k = 0; k < KNB; ++k) {
                c0 += w[k] * hlo(nei[k][j]);
                c1 += w[k] * hhi(nei[k][j]);
            }
            mrow[j] = packh2(c0, c1);
        }
    }
}

// ---------------------------------------------------------------------------
// a_nei[a] = sum_k msg[agraph[a][k]]
// ---------------------------------------------------------------------------
__global__ void gather_sum_h_k(const f16* __restrict__ msg,
                               const int* __restrict__ agraph,
                               f16* __restrict__ out) {
    int idx = blockIdx.x * 256 + threadIdx.x;
    if (idx >= NATOMS * (HP / 2)) return;
    int a = idx / (HP / 2), c = idx - a * (HP / 2);
    const int* g = agraph + (size_t)a * KNB;
    float s0 = 0.f, s1 = 0.f;
#pragma unroll
    for (int k = 0; k < KNB; ++k) {
        u32 u = *(const u32*)(msg + (size_t)g[k] * HP + c * 2);
        s0 += hlo(u); s1 += hhi(u);
    }
    ((u32*)out)[idx] = packh2(s0, s1);
}

// ---------------------------------------------------------------------------
__global__ void conv_pad_k(const float* __restrict__ src, f16* __restrict__ dst,
                           int R, int C, int CP) {
    int idx = blockIdx.x * 256 + threadIdx.x;
    if (idx >= R * CP) return;
    int r = idx / CP, c = idx - r * CP;
    dst[idx] = (f16)(c < C ? src[(size_t)r * C + c] : 0.f);
}

// ---------------------------------------------------------------------------
// Weight prep -> f16, padded, K-contiguous ([N][K]) layouts.
// mode 0: WiT[320][192]  <- W_i[300][158]
// mode 1: WmaT[1280][320]<- W_ma[n][h][d] at row n*320+d, col h
// mode 2: WhT[320][1280] <- W_h[h_out][n*300+d] at row h_out, col n*320+d
// mode 3: WoA[320][192]  <- W_o cols 0..143
// mode 4: WoB[320][320]  <- W_o cols 144..443
// else:   [320][320]     <- [300][300]
// ---------------------------------------------------------------------------
__global__ void prep_w_k(const float* __restrict__ src, f16* __restrict__ dst,
                         int mode, int R, int CK) {
    int idx = blockIdx.x * 256 + threadIdx.x;
    if (idx >= R * CK) return;
    int r = idx / CK, c = idx - r * CK;
    float v = 0.f;
    if (mode == 0) {
        if (r < HID && c < BONDIN) v = src[r * BONDIN + c];
    } else if (mode == 1) {
        int n = r / HP, d = r - n * HP;
        if (d < HID && c < HID) v = src[((size_t)n * HID + c) * HID + d];
    } else if (mode == 2) {
        int n = c / HP, d = c - n * HP;
        if (r < HID && d < HID) v = src[(size_t)r * (NH * HID) + n * HID + d];
    } else if (mode == 3) {
        if (r < HID && c < AFD) v = src[r * (AFD + HID) + c];
    } else if (mode == 4) {
        if (r < HID && c < HID) v = src[r * (AFD + HID) + AFD + c];
    } else {
        if (r < HID && c < HID) v = src[r * HID + c];
    }
    dst[idx] = (f16)v;
}

// ---------------------------------------------------------------------------
// MFMA molecule attention (proven round 4).
// ---------------------------------------------------------------------------
__global__ __launch_bounds__(256) void mol_attn_mfma_k(
    const f16* __restrict__ atomHh,
    const f16* __restrict__ ah2h,
    f16* __restrict__ comp2h)
{
    __shared__ f16 sCur[64 * 320];
    __shared__ float sP[64][66];
    const int tid  = threadIdx.x;
    const int lane = tid & 63;
    const int wv   = tid >> 6;
    const int m    = blockIdx.x;
    const int rl   = lane & 15, cl = lane >> 4;

#pragma unroll
    for (int i = 0; i < 10; ++i) {
        int g   = i * 256 + wv * 64 + lane;
        int row = g / 40, c = g - row * 40;
        int grow = m * APM + row; grow = grow < NATOMS ? grow : NATOMS - 1;
        const f16* src = atomHh + (size_t)grow * HP + ((c ^ (row & 7)) << 3);
        gl2lds16(src, (char*)sCur + (size_t)(i * 256 + wv * 64) * 16);
    }
    __syncthreads();

    f32x4 acc[4];
#pragma unroll
    for (int nf = 0; nf < 4; ++nf) acc[nf] = (f32x4){0.f, 0.f, 0.f, 0.f};
    int qrow = m * APM + wv * 16 + rl;
    qrow = qrow < NATOMS ? qrow : NATOMS - 1;
    const f16* qbase = ah2h + (size_t)qrow * HP;
#pragma unroll
    for (int kh = 0; kh < 10; ++kh) {
        f16x8 aq = *(const f16x8*)(qbase + kh * 32 + cl * 8);
#pragma unroll
        for (int nf = 0; nf < 4; ++nf) {
            int brow = nf * 16 + rl;
            int ch   = (kh * 4 + cl) ^ (brow & 7);
            f16x8 bv = *(const f16x8*)&sCur[brow * 320 + ch * 8];
            acc[nf] = __builtin_amdgcn_mfma_f32_16x16x32_f16(aq, bv, acc[nf], 0, 0, 0);
        }
    }

#pragma unroll
    for (int r = 0; r < 4; ++r) {
        float s[4];
#pragma unroll
        for (int nf = 0; nf < 4; ++nf) {
            s[nf] = acc[nf][r];
            if (nf == 3 && rl >= 2) s[nf] = -1e30f;
        }
        float mx = fmaxf(fmaxf(s[0], s[1]), fmaxf(s[2], s[3]));
#pragma unroll
        for (int msk = 1; msk < 16; msk <<= 1) mx = fmaxf(mx, __shfl_xor(mx, msk));
        float e[4], sum = 0.f;
#pragma unroll
        for (int nf = 0; nf < 4; ++nf) { e[nf] = __expf(s[nf] - mx); sum += e[nf]; }
#pragma unroll
        for (int msk = 1; msk < 16; msk <<= 1) sum += __shfl_xor(sum, msk);
        float inv = 1.f / sum;
        int a = wv * 16 + cl * 4 + r;
#pragma unroll
        for (int nf = 0; nf < 4; ++nf) sP[a][nf * 16 + rl] = e[nf] * inv;
    }
    __syncthreads();

    const int a  = tid >> 2, hq = tid & 3;
    const bool aval = a < APM;
    const size_t orow = (size_t)(m * APM + a) * HP;
#pragma unroll
    for (int p = 0; p < 2; ++p) {
        float av[40];
#pragma unroll
        for (int i = 0; i < 40; ++i) av[i] = 0.f;
        const int ch0 = p * 20 + hq * 5;
        for (int b = 0; b < APM; ++b) {
            float w = sP[a][b];
#pragma unroll
            for (int i = 0; i < 5; ++i) {
                int ch = (ch0 + i) ^ (b & 7);
                f16x8 cv = *(const f16x8*)&sCur[b * 320 + ch * 8];
#pragma unroll
                for (int j = 0; j < 8; ++j) av[i * 8 + j] += w * (float)cv[j];
            }
        }
        if (aval) {
#pragma unroll
            for (int i = 0; i < 5; ++i) {
                f16x8 o;
#pragma unroll
                for (int j = 0; j < 8; ++j) o[j] = (f16)av[i * 8 + j];
                *(f16x8*)&comp2h[orow + p * 160 + hq * 40 + i * 8] = o;
            }
        }
    }
}

__global__ void mol_reduce_k(const float* __restrict__ atomH,
                             const float* __restrict__ atth,
                             float* __restrict__ out) {
    const int m = blockIdx.x;
    for (int h = threadIdx.x; h < HID; h += 256) {
        float s = 0.f;
        for (int a = 0; a < APM; ++a) {
            size_t i = (size_t)(m * APM + a) * HP + h;
            s += atomH[i] + atth[i];
        }
        out[(size_t)m * HID + h] = s * (1.f / APM);
    }
}

// ---------------------------------------------------------------------------
extern "C" void kernel_launch(void* const* d_in, const int* in_sizes, int n_in,
                              void* d_out, int out_size, void* d_ws, size_t ws_size,
                              hipStream_t stream) {
    const float* fatoms = (const float*)d_in[0];
    const float* fbonds = (const float*)d_in[1];
    const int*   agraph = (const int*)d_in[2];
    const int*   bgraph = (const int*)d_in[3];
    const float* W_i    = (const float*)d_in[4];
    const float* W_ma   = (const float*)d_in[5];
    const float* W_h    = (const float*)d_in[6];
    const float* W_o    = (const float*)d_in[7];
    const float* b_o    = (const float*)d_in[8];
    const float* W_a    = (const float*)d_in[9];
    const float* W_b    = (const float*)d_in[10];
    const float* b_b    = (const float*)d_in[11];
    float* out = (float*)d_out;

    // ---- workspace layout (round-4 proven) ----
    char* ws = (char*)d_ws;
    f16* fbondsh = (f16*)ws;
    f16* mtall   = (f16*)ws;
    f16* aneih   = (f16*)ws;                         // [30000][320] f16
    f16* fatomsh = (f16*)(ws + 19200000);            // [30000][192] f16
    float* atomH = (float*)(ws + 30720000);          // [30000][320] f32
    f16* atomHh  = (f16*)(ws + 69120000);            // [30000][320] f16
    f16* ah2h    = (f16*)(ws + 88320000);            // [30000][320] f16
    f16* comp2h  = (f16*)(ws + 126720000);           // [30000][320] f16
    f16* binh    = (f16*)(ws + 153600000);
    float* atth  = (float*)(ws + 153600000);
    f16* msgh    = (f16*)(ws + 192000000);
    char* wb = ws + 230400000;
    f16* WiT  = (f16*)(wb);
    f16* WmaT = (f16*)(wb + 122880);
    f16* WhT  = (f16*)(wb + 942080);
    f16* WoA  = (f16*)(wb + 1761280);
    f16* WoB  = (f16*)(wb + 1884160);
    f16* Wa   = (f16*)(wb + 2088960);
    f16* Wb   = (f16*)(wb + 2293760);

    // ---- weight/input prep ----
    prep_w_k<<<dim3((320 * 192 + 255) / 256), dim3(256), 0, stream>>>(W_i, WiT, 0, 320, 192);
    prep_w_k<<<dim3((1280 * 320 + 255) / 256), dim3(256), 0, stream>>>(W_ma, WmaT, 1, 1280, 320);
    prep_w_k<<<dim3((320 * 1280 + 255) / 256), dim3(256), 0, stream>>>(W_h, WhT, 2, 320, 1280);
    prep_w_k<<<dim3((320 * 192 + 255) / 256), dim3(256), 0, stream>>>(W_o, WoA, 3, 320, 192);
    prep_w_k<<<dim3((320 * 320 + 255) / 256), dim3(256), 0, stream>>>(W_o, WoB, 4, 320, 320);
    prep_w_k<<<dim3((320 * 320 + 255) / 256), dim3(256), 0, stream>>>(W_a, Wa, 5, 320, 320);
    prep_w_k<<<dim3((320 * 320 + 255) / 256), dim3(256), 0, stream>>>(W_b, Wb, 6, 320, 320);
    conv_pad_k<<<dim3((E_BONDS * 192 + 255) / 256), dim3(256), 0, stream>>>(
        fbonds, fbondsh, E_BONDS, BONDIN, 192);

    // ---- binput/message0 ----
    mfma_gemm_k<128, 2><<<dim3(swz_grid(3, 469)), dim3(256), 0, stream>>>(
        fbondsh, 192, WiT, 192, E_BONDS, 320, 192, HP, 3, 469,
        nullptr, binh, nullptr, nullptr, msgh);

    // ---- 3 message-passing iterations (split pipeline) ----
    for (int it = 0; it < 3; ++it) {
        mfma_gemm_k<128, 1><<<dim3(swz_grid(10, 469)), dim3(256), 0, stream>>>(
            msgh, HP, WmaT, HP, E_BONDS, NH * HP, HP, NH * HP, 10, 469,
            nullptr, mtall, nullptr, nullptr, nullptr);
        score_comp_k<<<dim3(E_BONDS / 16), dim3(256), 0, stream>>>(msgh, mtall, bgraph);
        mfma_gemm_k<128, 3><<<dim3(swz_grid(3, 469)), dim3(256), 0, stream>>>(
            mtall, NH * HP, WhT, NH * HP, E_BONDS, HP, NH * HP, HP, 3, 469,
            nullptr, msgh, nullptr, binh, nullptr);
    }

    // ---- atom stage ----
    gather_sum_h_k<<<dim3((NATOMS * 160 + 255) / 256), dim3(256), 0, stream>>>(msgh, agraph, aneih);
    conv_pad_k<<<dim3((NATOMS * 192 + 255) / 256), dim3(256), 0, stream>>>(
        fatoms, fatomsh, NATOMS, AFD, 192);
    mfma_gemm_k<128, 0><<<dim3(swz_grid(3, 235)), dim3(256), 0, stream>>>(
        fatomsh, 192, WoA, 192, NATOMS, 320, 192, HP, 3, 235,
        atomH, nullptr, nullptr, nullptr, nullptr);
    mfma_gemm_k<128, 4><<<dim3(swz_grid(3, 235)), dim3(256), 0, stream>>>(
        aneih, HP, WoB, HP, NATOMS, 320, HP, HP, 3, 235,
        atomH, atomHh, b_o, nullptr, nullptr);

    // ---- molecule attention ----
    mfma_gemm_k<128, 1><<<dim3(swz_grid(3, 235)), dim3(256), 0, stream>>>(
        atomHh, HP, Wa, HP, NATOMS, 320, HP, HP, 3, 235,
        nullptr, ah2h, nullptr, nullptr, nullptr);
    mol_attn_mfma_k<<<dim3(NMOLS), dim3(256), 0, stream>>>(atomHh, ah2h, comp2h);
    mfma_gemm_k<128, 5><<<dim3(swz_grid(3, 235)), dim3(256), 0, stream>>>(
        comp2h, HP, Wb, HP, NATOMS, 320, HP, HP, 3, 235,
        atth, nullptr, b_b, nullptr, nullptr);
    mol_reduce_k<<<dim3(NMOLS), dim3(256), 0, stream>>>(atomH, atth, out);
}

// Round 14
// 929.568 us; speedup vs baseline: 2.3273x; 1.0276x over previous
//
#include <hip/hip_runtime.h>
#include <hip/hip_bf16.h>
#include <math.h>

// Problem constants
#define HID       300
#define HP        320
#define NH        4
#define E_BONDS   60000
#define NATOMS    30000
#define KNB       6
#define NMOLS     600
#define APM       50
#define AFD       144
#define BONDIN    158

typedef unsigned short u16;
typedef unsigned int   u32;
typedef _Float16 f16;
typedef f16   f16x8 __attribute__((ext_vector_type(8)));
typedef float f32x4 __attribute__((ext_vector_type(4)));

// ---------------- helpers ----------------
__device__ inline float hlo(u32 u) { union { u32 i; f16 h[2]; } c; c.i = u; return (float)c.h[0]; }
__device__ inline float hhi(u32 u) { union { u32 i; f16 h[2]; } c; c.i = u; return (float)c.h[1]; }
__device__ inline u32 packh2(float a, float b) {
    union { u32 i; f16 h[2]; } c; c.h[0] = (f16)a; c.h[1] = (f16)b; return c.i;
}

__device__ inline void gl2lds16(const void* g, void* l) {
    __builtin_amdgcn_global_load_lds(
        (const __attribute__((address_space(1))) void*)g,
        (__attribute__((address_space(3))) void*)l, 16, 0, 0);
}

// ---------------------------------------------------------------------------
// MFMA GEMM (round-13 proven: BN=128, 4 waves, launch_bounds(256,4) => 124
// total regs/wave, 16 waves/CU; XCD-aware swizzle).
// 1D grid; linear block b -> xcd=b&7, q=b>>3, xb=q%nbx, yb=(q/nbx)*8+xcd.
// EPI: 0 Cf=v | 1 Ch=h(v) | 2 Ch=h(v),out2=h(relu v) | 3 v+=resid,relu,Ch
//      4 v+=Cf+bias,relu,Cf&Ch | 5 v+=bias,relu,Cf | 6 v+=bias,relu,Ch
// ---------------------------------------------------------------------------
template <int BN, int EPI>
__global__ __launch_bounds__(256, 4) void mfma_gemm_k(
    const f16* __restrict__ A, int lda,
    const f16* __restrict__ B, int ldb,
    int M, int Nb, int K, int ldc,
    int nbx, int mby,
    float* __restrict__ Cf, f16* __restrict__ Ch,
    const float* __restrict__ bias,
    const f16* __restrict__ resid,
    f16* __restrict__ out2)
{
    constexpr int NF = BN / 32;
    __shared__ f16 sA[128 * 64];
    __shared__ f16 sB[BN * 64];
    const int b    = blockIdx.x;
    const int xcd  = b & 7;
    const int q    = b >> 3;
    const int xb   = q % nbx;
    const int yb   = (q / nbx) * 8 + xcd;
    if (yb >= mby) return;
    const int tid  = threadIdx.x;
    const int lane = tid & 63;
    const int wv   = tid >> 6;
    const int wm   = wv >> 1, wn = wv & 1;
    const int m0   = yb * 128, n0 = xb * BN;

    f32x4 acc[4][NF];
#pragma unroll
    for (int i = 0; i < 4; ++i)
#pragma unroll
        for (int j = 0; j < NF; ++j) acc[i][j] = (f32x4){0.f, 0.f, 0.f, 0.f};

    for (int k0 = 0; k0 < K; k0 += 64) {
        __syncthreads();
#pragma unroll
        for (int i = 0; i < 4; ++i) {
            int o   = (((i * 4 + wv) * 64) + lane) * 16;
            int row = o >> 7;
            int p   = (o >> 4) & 7;
            int gr  = m0 + row; gr = gr < M ? gr : M - 1;
            const f16* g = A + (size_t)gr * lda + k0 + ((p ^ (row & 7)) << 3);
            gl2lds16(g, (char*)sA + (i * 4 + wv) * 1024);
        }
#pragma unroll
        for (int i = 0; i < BN / 32; ++i) {
            int o   = (((i * 4 + wv) * 64) + lane) * 16;
            int row = o >> 7;
            int p   = (o >> 4) & 7;
            int gr  = n0 + row; gr = gr < Nb ? gr : Nb - 1;
            const f16* g = B + (size_t)gr * ldb + k0 + ((p ^ (row & 7)) << 3);
            gl2lds16(g, (char*)sB + (i * 4 + wv) * 1024);
        }
        __syncthreads();

        const int rl = lane & 15, cl = lane >> 4;
#pragma unroll
        for (int kh = 0; kh < 2; ++kh) {
            f16x8 af[4], bfr[NF];
#pragma unroll
            for (int mf = 0; mf < 4; ++mf) {
                int row = wm * 64 + mf * 16 + rl;
                int ch  = (kh * 4 + cl) ^ (row & 7);
                af[mf]  = *(const f16x8*)&sA[row * 64 + ch * 8];
            }
#pragma unroll
            for (int nf = 0; nf < NF; ++nf) {
                int row = wn * (BN / 2) + nf * 16 + rl;
                int ch  = (kh * 4 + cl) ^ (row & 7);
                bfr[nf] = *(const f16x8*)&sB[row * 64 + ch * 8];
            }
#pragma unroll
            for (int mf = 0; mf < 4; ++mf)
#pragma unroll
                for (int nf = 0; nf < NF; ++nf)
                    acc[mf][nf] = __builtin_amdgcn_mfma_f32_16x16x32_f16(
                        af[mf], bfr[nf], acc[mf][nf], 0, 0, 0);
        }
    }

    const int rl = lane & 15, cl = lane >> 4;
#pragma unroll
    for (int mf = 0; mf < 4; ++mf) {
#pragma unroll
        for (int r = 0; r < 4; ++r) {
            int gm = m0 + wm * 64 + mf * 16 + cl * 4 + r;
            if (gm >= M) continue;
#pragma unroll
            for (int nf = 0; nf < NF; ++nf) {
                int gn = n0 + wn * (BN / 2) + nf * 16 + rl;
                if (gn >= ldc) continue;
                float v = acc[mf][nf][r];
                size_t ci = (size_t)gm * ldc + gn;
                if (EPI == 0) {
                    Cf[ci] = v;
                } else if (EPI == 1) {
                    Ch[ci] = (f16)v;
                } else if (EPI == 2) {
                    Ch[ci] = (f16)v;
                    out2[ci] = (f16)fmaxf(v, 0.f);
                } else if (EPI == 3) {
                    v += (float)resid[ci];
                    Ch[ci] = (f16)fmaxf(v, 0.f);
                } else if (EPI == 4) {
                    v += Cf[ci];
                    v += (gn < HID) ? bias[gn] : 0.f;
                    v = fmaxf(v, 0.f);
                    Cf[ci] = v; Ch[ci] = (f16)v;
                } else if (EPI == 5) {
                    v += (gn < HID) ? bias[gn] : 0.f;
                    Cf[ci] = fmaxf(v, 0.f);
                } else {                      // EPI == 6
                    v += (gn < HID) ? bias[gn] : 0.f;
                    Ch[ci] = (f16)fmaxf(v, 0.f);
                }
            }
        }
    }
}

// grid size helper (host)
static inline int swz_grid(int nbx, int mby) { return nbx * 8 * ((mby + 7) / 8); }

// ---------------------------------------------------------------------------
// Fused score/softmax/comp, all 4 heads; nei gathered once per bond, held
// across heads (256-thr kernel, no spill — proven).
// ---------------------------------------------------------------------------
__global__ __launch_bounds__(256) void score_comp_k(
    const f16* __restrict__ msg,     // [E][320] f16
    f16* __restrict__ mtc,           // [E][1280] f16: in mt, out comp
    const int* __restrict__ bgraph)
{
    const int tid = threadIdx.x;
    const int e   = blockIdx.x * 16 + (tid >> 4);
    const int t   = tid & 15;

    u32 nei[KNB][10];
#pragma unroll
    for (int k = 0; k < KNB; ++k) {
        int nb = bgraph[e * KNB + k];
        const u32* p = (const u32*)(msg + (size_t)nb * HP) + t * 10;
#pragma unroll
        for (int j = 0; j < 10; ++j) nei[k][j] = p[j];
    }

    for (int n = 0; n < NH; ++n) {
        u32* mrow = (u32*)(mtc + (size_t)e * (NH * HP) + n * HP) + t * 10;
        u32 mt[10];
#pragma unroll
        for (int j = 0; j < 10; ++j) mt[j] = mrow[j];

        float pk[KNB] = {0.f, 0.f, 0.f, 0.f, 0.f, 0.f};
#pragma unroll
        for (int j = 0; j < 10; ++j) {
            float m0 = hlo(mt[j]), m1 = hhi(mt[j]);
#pragma unroll
            for (int k = 0; k < KNB; ++k)
                pk[k] += hlo(nei[k][j]) * m0 + hhi(nei[k][j]) * m1;
        }
#pragma unroll
        for (int s = 1; s < 16; s <<= 1)
#pragma unroll
            for (int k = 0; k < KNB; ++k) pk[k] += __shfl_xor(pk[k], s);

        float mx = pk[0];
#pragma unroll
        for (int k = 1; k < KNB; ++k) mx = fmaxf(mx, pk[k]);
        float w[KNB], sum = 0.f;
#pragma unroll
        for (int k = 0; k < KNB; ++k) { w[k] = __expf(pk[k] - mx); sum += w[k]; }
        float inv = 1.f / sum;
#pragma unroll
        for (int k = 0; k < KNB; ++k) w[k] *= inv;

#pragma unroll
        for (int j = 0; j < 10; ++j) {
            float c0 = 0.f, c1 = 0.f;
#pragma unroll
            for (int k = 0; k < KNB; ++k) {
                c0 += w[k] * hlo(nei[k][j]);
                c1 += w[k] * hhi(nei[k][j]);
            }
            mrow[j] = packh2(c0, c1);
        }
    }
}

// ---------------------------------------------------------------------------
// a_nei into combined buffer: fat512[a][192 + c] = sum_k msg[agraph[a][k]][c]
// (row stride 512 f16 = 256 u32; column base 192 f16 = 96 u32)
// ---------------------------------------------------------------------------
__global__ void gather_sum_h_k(const f16* __restrict__ msg,
                               const int* __restrict__ agraph,
                               f16* __restrict__ out512) {
    int idx = blockIdx.x * 256 + threadIdx.x;
    if (idx >= NATOMS * (HP / 2)) return;
    int a = idx / (HP / 2), c = idx - a * (HP / 2);
    const int* g = agraph + (size_t)a * KNB;
    float s0 = 0.f, s1 = 0.f;
#pragma unroll
    for (int k = 0; k < KNB; ++k) {
        u32 u = *(const u32*)(msg + (size_t)g[k] * HP + c * 2);
        s0 += hlo(u); s1 += hhi(u);
    }
    ((u32*)out512)[(size_t)a * 256 + 96 + c] = packh2(s0, s1);
}

// ---------------------------------------------------------------------------
// fp32 [R][C] -> f16 dst rows of stride RP, cols [0,CP) zero-padded
// ---------------------------------------------------------------------------
__global__ void conv_pad_k(const float* __restrict__ src, f16* __restrict__ dst,
                           int R, int C, int CP, int RP) {
    int idx = blockIdx.x * 256 + threadIdx.x;
    if (idx >= R * CP) return;
    int r = idx / CP, c = idx - r * CP;
    dst[(size_t)r * RP + c] = (f16)(c < C ? src[(size_t)r * C + c] : 0.f);
}

// ---------------------------------------------------------------------------
// Weight prep -> f16, padded, K-contiguous ([N][K]) layouts.
// mode 0: WiT[320][192]   <- W_i[300][158]
// mode 1: WmaT[1280][320] <- W_ma[n][h][d] at row n*320+d, col h
// mode 2: WhT[320][1280]  <- W_h[h_out][n*300+d] at row h_out, col n*320+d
// mode 7: Wo512[320][512] <- [W_o[:, :144] pad192 | W_o[:, 144:444] pad320]
// else:   [320][320]      <- [300][300]
// ---------------------------------------------------------------------------
__global__ void prep_w_k(const float* __restrict__ src, f16* __restrict__ dst,
                         int mode, int R, int CK) {
    int idx = blockIdx.x * 256 + threadIdx.x;
    if (idx >= R * CK) return;
    int r = idx / CK, c = idx - r * CK;
    float v = 0.f;
    if (mode == 0) {
        if (r < HID && c < BONDIN) v = src[r * BONDIN + c];
    } else if (mode == 1) {
        int n = r / HP, d = r - n * HP;
        if (d < HID && c < HID) v = src[((size_t)n * HID + c) * HID + d];
    } else if (mode == 2) {
        int n = c / HP, d = c - n * HP;
        if (r < HID && d < HID) v = src[(size_t)r * (NH * HID) + n * HID + d];
    } else if (mode == 7) {
        if (r < HID) {
            if (c < AFD) v = src[r * (AFD + HID) + c];
            else if (c >= 192 && c < 192 + HID) v = src[r * (AFD + HID) + AFD + (c - 192)];
        }
    } else {
        if (r < HID && c < HID) v = src[r * HID + c];
    }
    dst[idx] = (f16)v;
}

// ---------------------------------------------------------------------------
// MFMA molecule attention (proven round 4).
// ---------------------------------------------------------------------------
__global__ __launch_bounds__(256) void mol_attn_mfma_k(
    const f16* __restrict__ atomHh,
    const f16* __restrict__ ah2h,
    f16* __restrict__ comp2h)
{
    __shared__ f16 sCur[64 * 320];
    __shared__ float sP[64][66];
    const int tid  = threadIdx.x;
    const int lane = tid & 63;
    const int wv   = tid >> 6;
    const int m    = blockIdx.x;
    const int rl   = lane & 15, cl = lane >> 4;

#pragma unroll
    for (int i = 0; i < 10; ++i) {
        int g   = i * 256 + wv * 64 + lane;
        int row = g / 40, c = g - row * 40;
        int grow = m * APM + row; grow = grow < NATOMS ? grow : NATOMS - 1;
        const f16* src = atomHh + (size_t)grow * HP + ((c ^ (row & 7)) << 3);
        gl2lds16(src, (char*)sCur + (size_t)(i * 256 + wv * 64) * 16);
    }
    __syncthreads();

    f32x4 acc[4];
#pragma unroll
    for (int nf = 0; nf < 4; ++nf) acc[nf] = (f32x4){0.f, 0.f, 0.f, 0.f};
    int qrow = m * APM + wv * 16 + rl;
    qrow = qrow < NATOMS ? qrow : NATOMS - 1;
    const f16* qbase = ah2h + (size_t)qrow * HP;
#pragma unroll
    for (int kh = 0; kh < 10; ++kh) {
        f16x8 aq = *(const f16x8*)(qbase + kh * 32 + cl * 8);
#pragma unroll
        for (int nf = 0; nf < 4; ++nf) {
            int brow = nf * 16 + rl;
            int ch   = (kh * 4 + cl) ^ (brow & 7);
            f16x8 bv = *(const f16x8*)&sCur[brow * 320 + ch * 8];
            acc[nf] = __builtin_amdgcn_mfma_f32_16x16x32_f16(aq, bv, acc[nf], 0, 0, 0);
        }
    }

#pragma unroll
    for (int r = 0; r < 4; ++r) {
        float s[4];
#pragma unroll
        for (int nf = 0; nf < 4; ++nf) {
            s[nf] = acc[nf][r];
            if (nf == 3 && rl >= 2) s[nf] = -1e30f;
        }
        float mx = fmaxf(fmaxf(s[0], s[1]), fmaxf(s[2], s[3]));
#pragma unroll
        for (int msk = 1; msk < 16; msk <<= 1) mx = fmaxf(mx, __shfl_xor(mx, msk));
        float e[4], sum = 0.f;
#pragma unroll
        for (int nf = 0; nf < 4; ++nf) { e[nf] = __expf(s[nf] - mx); sum += e[nf]; }
#pragma unroll
        for (int msk = 1; msk < 16; msk <<= 1) sum += __shfl_xor(sum, msk);
        float inv = 1.f / sum;
        int a = wv * 16 + cl * 4 + r;
#pragma unroll
        for (int nf = 0; nf < 4; ++nf) sP[a][nf * 16 + rl] = e[nf] * inv;
    }
    __syncthreads();

    const int a  = tid >> 2, hq = tid & 3;
    const bool aval = a < APM;
    const size_t orow = (size_t)(m * APM + a) * HP;
#pragma unroll
    for (int p = 0; p < 2; ++p) {
        float av[40];
#pragma unroll
        for (int i = 0; i < 40; ++i) av[i] = 0.f;
        const int ch0 = p * 20 + hq * 5;
        for (int b = 0; b < APM; ++b) {
            float w = sP[a][b];
#pragma unroll
            for (int i = 0; i < 5; ++i) {
                int ch = (ch0 + i) ^ (b & 7);
                f16x8 cv = *(const f16x8*)&sCur[b * 320 + ch * 8];
#pragma unroll
                for (int j = 0; j < 8; ++j) av[i * 8 + j] += w * (float)cv[j];
            }
        }
        if (aval) {
#pragma unroll
            for (int i = 0; i < 5; ++i) {
                f16x8 o;
#pragma unroll
                for (int j = 0; j < 8; ++j) o[j] = (f16)av[i * 8 + j];
                *(f16x8*)&comp2h[orow + p * 160 + hq * 40 + i * 8] = o;
            }
        }
    }
}

// ---------------------------------------------------------------------------
// mol_vecs[m][h] = sum_a (atomHh + atthh)[m*APM+a][h] / APM   (f16 inputs)
// ---------------------------------------------------------------------------
__global__ void mol_reduce_k(const f16* __restrict__ atomHh,
                             const f16* __restrict__ atthh,
                             float* __restrict__ out) {
    const int m = blockIdx.x;
    for (int h = threadIdx.x; h < HID; h += 256) {
        float s = 0.f;
        for (int a = 0; a < APM; ++a) {
            size_t i = (size_t)(m * APM + a) * HP + h;
            s += (float)atomHh[i] + (float)atthh[i];
        }
        out[(size_t)m * HID + h] = s * (1.f / APM);
    }
}

// ---------------------------------------------------------------------------
extern "C" void kernel_launch(void* const* d_in, const int* in_sizes, int n_in,
                              void* d_out, int out_size, void* d_ws, size_t ws_size,
                              hipStream_t stream) {
    const float* fatoms = (const float*)d_in[0];
    const float* fbonds = (const float*)d_in[1];
    const int*   agraph = (const int*)d_in[2];
    const int*   bgraph = (const int*)d_in[3];
    const float* W_i    = (const float*)d_in[4];
    const float* W_ma   = (const float*)d_in[5];
    const float* W_h    = (const float*)d_in[6];
    const float* W_o    = (const float*)d_in[7];
    const float* b_o    = (const float*)d_in[8];
    const float* W_a    = (const float*)d_in[9];
    const float* W_b    = (const float*)d_in[10];
    const float* b_b    = (const float*)d_in[11];
    float* out = (float*)d_out;

    // ---- workspace layout ----
    char* ws = (char*)d_ws;
    f16* fbondsh = (f16*)ws;                         // [60000][192] (pre-MP)
    f16* mtall   = (f16*)ws;                         // [60000][1280] (MP)
    f16* fat512  = (f16*)ws;                         // [30000][512] (post-MP)
    f16* atomHh  = (f16*)(ws + 115200000);           // [30000][320] f16
    f16* ah2h    = (f16*)(ws + 134400000);           // [30000][320] f16
    f16* comp2h  = (f16*)(ws + 153600000);           // [30000][320] f16
    f16* atthh   = (f16*)(ws + 172800000);           // [30000][320] f16
    f16* binh    = (f16*)(ws + 153600000);           // [60000][320] (MP; dead before comp2h)
    f16* msgh    = (f16*)(ws + 192000000);           // [60000][320]
    char* wb = ws + 230400000;
    f16* WiT   = (f16*)(wb);                         // 122880
    f16* WmaT  = (f16*)(wb + 122880);                // 819200
    f16* WhT   = (f16*)(wb + 942080);                // 819200
    f16* Wo512 = (f16*)(wb + 1761280);               // 327680
    f16* Wa    = (f16*)(wb + 2088960);               // 204800
    f16* Wb    = (f16*)(wb + 2293760);               // 204800

    // ---- weight/input prep ----
    prep_w_k<<<dim3((320 * 192 + 255) / 256), dim3(256), 0, stream>>>(W_i, WiT, 0, 320, 192);
    prep_w_k<<<dim3((1280 * 320 + 255) / 256), dim3(256), 0, stream>>>(W_ma, WmaT, 1, 1280, 320);
    prep_w_k<<<dim3((320 * 1280 + 255) / 256), dim3(256), 0, stream>>>(W_h, WhT, 2, 320, 1280);
    prep_w_k<<<dim3((320 * 512 + 255) / 256), dim3(256), 0, stream>>>(W_o, Wo512, 7, 320, 512);
    prep_w_k<<<dim3((320 * 320 + 255) / 256), dim3(256), 0, stream>>>(W_a, Wa, 5, 320, 320);
    prep_w_k<<<dim3((320 * 320 + 255) / 256), dim3(256), 0, stream>>>(W_b, Wb, 6, 320, 320);
    conv_pad_k<<<dim3((E_BONDS * 192 + 255) / 256), dim3(256), 0, stream>>>(
        fbonds, fbondsh, E_BONDS, BONDIN, 192, 192);

    // ---- binput/message0 ----
    mfma_gemm_k<128, 2><<<dim3(swz_grid(3, 469)), dim3(256), 0, stream>>>(
        fbondsh, 192, WiT, 192, E_BONDS, 320, 192, HP, 3, 469,
        nullptr, binh, nullptr, nullptr, msgh);

    // ---- 3 message-passing iterations (split pipeline) ----
    for (int it = 0; it < 3; ++it) {
        mfma_gemm_k<128, 1><<<dim3(swz_grid(10, 469)), dim3(256), 0, stream>>>(
            msgh, HP, WmaT, HP, E_BONDS, NH * HP, HP, NH * HP, 10, 469,
            nullptr, mtall, nullptr, nullptr, nullptr);
        score_comp_k<<<dim3(E_BONDS / 16), dim3(256), 0, stream>>>(msgh, mtall, bgraph);
        mfma_gemm_k<128, 3><<<dim3(swz_grid(3, 469)), dim3(256), 0, stream>>>(
            mtall, NH * HP, WhT, NH * HP, E_BONDS, HP, NH * HP, HP, 3, 469,
            nullptr, msgh, nullptr, binh, nullptr);
    }

    // ---- atom stage: combined [fatoms | a_nei] @ Wo512^T, one K=512 GEMM ----
    gather_sum_h_k<<<dim3((NATOMS * 160 + 255) / 256), dim3(256), 0, stream>>>(
        msgh, agraph, fat512);
    conv_pad_k<<<dim3((NATOMS * 192 + 255) / 256), dim3(256), 0, stream>>>(
        fatoms, fat512, NATOMS, AFD, 192, 512);
    mfma_gemm_k<128, 6><<<dim3(swz_grid(3, 235)), dim3(256), 0, stream>>>(
        fat512, 512, Wo512, 512, NATOMS, 320, 512, HP, 3, 235,
        nullptr, atomHh, b_o, nullptr, nullptr);

    // ---- molecule attention ----
    mfma_gemm_k<128, 1><<<dim3(swz_grid(3, 235)), dim3(256), 0, stream>>>(
        atomHh, HP, Wa, HP, NATOMS, 320, HP, HP, 3, 235,
        nullptr, ah2h, nullptr, nullptr, nullptr);
    mol_attn_mfma_k<<<dim3(NMOLS), dim3(256), 0, stream>>>(atomHh, ah2h, comp2h);
    mfma_gemm_k<128, 6><<<dim3(swz_grid(3, 235)), dim3(256), 0, stream>>>(
        comp2h, HP, Wb, HP, NATOMS, 320, HP, HP, 3, 235,
        nullptr, atthh, b_b, nullptr, nullptr);
    mol_reduce_k<<<dim3(NMOLS), dim3(256), 0, stream>>>(atomHh, atthh, out);
}